// Round 3
// baseline (3148.622 us; speedup 1.0000x reference)
//
#include <hip/hip_runtime.h>
#include <hip/hip_cooperative_groups.h>
#include <cstddef>
#include <cstdint>

namespace cg = cooperative_groups;

#define LN_EPS 1e-5f
#define NB 512
#define NT 256

typedef __attribute__((ext_vector_type(8))) short bf16x8;
typedef __attribute__((ext_vector_type(4))) float f32x4;

__device__ __forceinline__ unsigned short f2bf(float f) {
    unsigned u = __float_as_uint(f);
    u += 0x7FFFu + ((u >> 16) & 1u);   // round-to-nearest-even
    return (unsigned short)(u >> 16);
}
__device__ __forceinline__ float bf2f(unsigned short s) {
    return __uint_as_float(((unsigned)s) << 16);
}
__device__ __forceinline__ float sigf(float x) { return 1.f / (1.f + __expf(-x)); }

// async global->LDS, 16B per lane. lds dest = wave-uniform base + lane*16.
__device__ __forceinline__ void gload_lds16(const void* g, void* l) {
    __builtin_amdgcn_global_load_lds(
        (const __attribute__((address_space(1))) unsigned int*)(unsigned long long)(uintptr_t)g,
        (__attribute__((address_space(3))) unsigned int*)(unsigned int)(uintptr_t)l,
        16, 0, 0);
}

// ===================== cooperative uber-kernel =========================================
struct UberArgs {
    const float *x, *kk, *nn, *mask;
    const float *iw1, *ib1, *iw2, *ib2, *iw3, *ib3;
    const float *mw1, *mb1, *mw2, *mb2, *mw3, *mb3;
    const float *wih, *whh, *bih, *bhh, *lng, *lnb;
    const float *vw1, *vb1, *vw2, *vb2, *vw3, *vb3;
    unsigned short *wm1, *wm2, *wm3, *wih_b, *whh_b, *wv1, *wv2;  // bf16 weights
    unsigned char *x8, *m8;
    unsigned short *msgp;    // bf16 K-split partials [4][BNH]
    unsigned short *hb;
    float *cb;
    float *init0, *embed0, *logit, *out;
    int N, B, iters;
    long long BNH;
};

// ---- prologue: casts, zeros, init MLP --------------------------------------------------
__device__ void prologue(const UberArgs& A, char* smem)
{
    const int tid = threadIdx.x;
    const long long gtid = (long long)blockIdx.x * NT + tid;
    const long long GT = (long long)NB * NT;
    const int N = A.N, B_ = A.B;

    // x -> fp8 (e4m3)
    const long long n8 = (long long)B_ * N * N / 8;
    for (long long i = gtid; i < n8; i += GT) {
        const float* s = A.x + i * 8;
        float4 a0 = *(const float4*)s;
        float4 b0 = *(const float4*)(s + 4);
        int lo = __builtin_amdgcn_cvt_pk_fp8_f32(a0.x, a0.y, 0, false);
        lo = __builtin_amdgcn_cvt_pk_fp8_f32(a0.z, a0.w, lo, true);
        int hi = __builtin_amdgcn_cvt_pk_fp8_f32(b0.x, b0.y, 0, false);
        hi = __builtin_amdgcn_cvt_pk_fp8_f32(b0.z, b0.w, hi, true);
        int2 o; o.x = lo; o.y = hi;
        *(int2*)(A.x8 + i * 8) = o;
    }
    // weights -> bf16
    {
        const float* srcs[7] = {A.mw1, A.mw2, A.mw3, A.wih, A.whh, A.vw1, A.vw2};
        unsigned short* dsts[7] = {A.wm1, A.wm2, A.wm3, A.wih_b, A.whh_b, A.wv1, A.wv2};
        const int ns[7] = {16384, 16384, 16384, 65536, 65536, 16384, 16384};
        for (int rg = 0; rg < 7; ++rg) {
            const float* s = srcs[rg]; unsigned short* d = dsts[rg];
            const int n4 = ns[rg] >> 2;
            for (long long i = gtid; i < n4; i += GT) {
                float4 v = *(const float4*)(s + i * 4);
                ushort4 o;
                o.x = f2bf(v.x); o.y = f2bf(v.y); o.z = f2bf(v.z); o.w = f2bf(v.w);
                *(ushort4*)(d + i * 4) = o;
            }
        }
    }
    // c = 0
    const long long nc4 = A.BNH >> 2;
    const float4 z4 = make_float4(0.f, 0.f, 0.f, 0.f);
    for (long long i = gtid; i < nc4; i += GT) ((float4*)A.cb)[i] = z4;
    if (blockIdx.x == 0 && tid < B_) A.logit[tid] = 0.f;

    // init MLP (2->128->128->128) + LN on the last B_ blocks
    if ((int)blockIdx.x >= NB - B_) {
        const int b = blockIdx.x - (NB - B_);
        float* s1 = (float*)smem;
        float* s2 = s1 + 128;
        float* red = s2 + 128;
        const bool act = tid < 128;
        const int j = tid;
        const float kv = A.kk[b], nv = A.nn[b];
        float h1 = 0.f, h2 = 0.f, o = 0.f;
        if (act) {
            h1 = A.iw1[j * 2 + 0] * kv + A.iw1[j * 2 + 1] * nv + A.ib1[j];
            h1 = h1 > 0.f ? h1 : 0.f;
            s1[j] = h1;
        }
        __syncthreads();
        if (act) {
            h2 = A.ib2[j];
            for (int q = 0; q < 128; ++q) h2 += A.iw2[j * 128 + q] * s1[q];
            h2 = h2 > 0.f ? h2 : 0.f;
            s2[j] = h2;
        }
        __syncthreads();
        if (act) {
            o = A.ib3[j];
            for (int q = 0; q < 128; ++q) o += A.iw3[j * 128 + q] * s2[q];
            A.init0[b * 128 + j] = o;
            red[j] = o;
        }
        __syncthreads();
        for (int s = 64; s > 0; s >>= 1) { if (tid < s) red[tid] += red[tid + s]; __syncthreads(); }
        const float mu = red[0] * (1.f / 128.f);
        __syncthreads();
        if (act) red[j] = (o - mu) * (o - mu);
        __syncthreads();
        for (int s = 64; s > 0; s >>= 1) { if (tid < s) red[tid] += red[tid + s]; __syncthreads(); }
        if (act) {
            const float var = red[0] * (1.f / 128.f);
            A.embed0[b * 128 + j] = (o - mu) * rsqrtf(var + LN_EPS) * A.lng[j] + A.lnb[j];
        }
    }
}

// ---- msg MLP on one 16-row tile; 4 waves col-split (2 out-tiles each); ebt -> m8 ------
__device__ __forceinline__ void msg_tile(const UberArgs& A, int tile,
                                         unsigned short (*ebt)[136], unsigned short (*act)[136])
{
    const int tid = threadIdx.x;
    const int lane = tid & 63, wave = tid >> 6;
    const int lr = lane & 15, lq = lane >> 4;
    const int r0 = tile * 16;
    const int N = A.N;
    bf16x8 a[4];
    f32x4 acc2[2];

    // layer 1: ebt -> act
#pragma unroll
    for (int s = 0; s < 4; ++s) a[s] = *(const bf16x8*)&ebt[lr][s * 32 + lq * 8];
    acc2[0] = (f32x4)(0.f); acc2[1] = (f32x4)(0.f);
#pragma unroll
    for (int s = 0; s < 4; ++s)
#pragma unroll
        for (int t = 0; t < 2; ++t) {
            const int orow = wave * 32 + t * 16 + lr;
            bf16x8 b = *(const bf16x8*)(A.wm1 + orow * 128 + s * 32 + lq * 8);
            acc2[t] = __builtin_amdgcn_mfma_f32_16x16x32_bf16(a[s], b, acc2[t], 0, 0, 0);
        }
#pragma unroll
    for (int t = 0; t < 2; ++t) {
        const int col = wave * 32 + t * 16 + lr;
        const float bb = A.mb1[col];
#pragma unroll
        for (int r = 0; r < 4; ++r) {
            float v = acc2[t][r] + bb; v = v > 0.f ? v : 0.f;
            act[lq * 4 + r][col] = f2bf(v);
        }
    }
    __syncthreads();
    // layer 2: act -> ebt (reuse)
#pragma unroll
    for (int s = 0; s < 4; ++s) a[s] = *(const bf16x8*)&act[lr][s * 32 + lq * 8];
    acc2[0] = (f32x4)(0.f); acc2[1] = (f32x4)(0.f);
#pragma unroll
    for (int s = 0; s < 4; ++s)
#pragma unroll
        for (int t = 0; t < 2; ++t) {
            const int orow = wave * 32 + t * 16 + lr;
            bf16x8 b = *(const bf16x8*)(A.wm2 + orow * 128 + s * 32 + lq * 8);
            acc2[t] = __builtin_amdgcn_mfma_f32_16x16x32_bf16(a[s], b, acc2[t], 0, 0, 0);
        }
    __syncthreads();   // all reads of act done before ebt rewritten below is fine; keep order strict
#pragma unroll
    for (int t = 0; t < 2; ++t) {
        const int col = wave * 32 + t * 16 + lr;
        const float bb = A.mb2[col];
#pragma unroll
        for (int r = 0; r < 4; ++r) {
            float v = acc2[t][r] + bb; v = v > 0.f ? v : 0.f;
            ebt[lq * 4 + r][col] = f2bf(v);
        }
    }
    __syncthreads();
    // layer 3: ebt -> m8 (fp8, [B][128][N])
#pragma unroll
    for (int s = 0; s < 4; ++s) a[s] = *(const bf16x8*)&ebt[lr][s * 32 + lq * 8];
    acc2[0] = (f32x4)(0.f); acc2[1] = (f32x4)(0.f);
#pragma unroll
    for (int s = 0; s < 4; ++s)
#pragma unroll
        for (int t = 0; t < 2; ++t) {
            const int orow = wave * 32 + t * 16 + lr;
            bf16x8 b = *(const bf16x8*)(A.wm3 + orow * 128 + s * 32 + lq * 8);
            acc2[t] = __builtin_amdgcn_mfma_f32_16x16x32_bf16(a[s], b, acc2[t], 0, 0, 0);
        }
    const int batch = r0 / N;
    const int rin0 = r0 - batch * N + lq * 4;
#pragma unroll
    for (int t = 0; t < 2; ++t) {
        const int col = wave * 32 + t * 16 + lr;
        const float bb = A.mb3[col];
        float v0 = acc2[t][0] + bb, v1 = acc2[t][1] + bb;
        float v2 = acc2[t][2] + bb, v3 = acc2[t][3] + bb;
        int pk = __builtin_amdgcn_cvt_pk_fp8_f32(v0, v1, 0, false);
        pk = __builtin_amdgcn_cvt_pk_fp8_f32(v2, v3, pk, true);
        *(unsigned int*)(A.m8 + (long long)(batch * 128 + col) * N + rin0) = (unsigned)pk;
    }
}

// ---- vote MLP on one 16-row tile; ebt -> atomicAdd(logit) -----------------------------
__device__ __forceinline__ void vote_tile(const UberArgs& A, int tile,
                                          unsigned short (*ebt)[136], unsigned short (*act)[136],
                                          float* sdot)
{
    const int tid = threadIdx.x;
    const int lane = tid & 63, wave = tid >> 6;
    const int lr = lane & 15, lq = lane >> 4;
    const int r0 = tile * 16;
    const int N = A.N;
    bf16x8 a[4];
    f32x4 acc2[2];

    // layer 1: ebt -> act
#pragma unroll
    for (int s = 0; s < 4; ++s) a[s] = *(const bf16x8*)&ebt[lr][s * 32 + lq * 8];
    acc2[0] = (f32x4)(0.f); acc2[1] = (f32x4)(0.f);
#pragma unroll
    for (int s = 0; s < 4; ++s)
#pragma unroll
        for (int t = 0; t < 2; ++t) {
            const int orow = wave * 32 + t * 16 + lr;
            bf16x8 b = *(const bf16x8*)(A.wv1 + orow * 128 + s * 32 + lq * 8);
            acc2[t] = __builtin_amdgcn_mfma_f32_16x16x32_bf16(a[s], b, acc2[t], 0, 0, 0);
        }
#pragma unroll
    for (int t = 0; t < 2; ++t) {
        const int col = wave * 32 + t * 16 + lr;
        const float bb = A.vb1[col];
#pragma unroll
        for (int r = 0; r < 4; ++r) {
            float v = acc2[t][r] + bb; v = v > 0.f ? v : 0.f;
            act[lq * 4 + r][col] = f2bf(v);
        }
    }
    __syncthreads();
    // layer 2 + dot(w3) + mask + reduce
#pragma unroll
    for (int s = 0; s < 4; ++s) a[s] = *(const bf16x8*)&act[lr][s * 32 + lq * 8];
    acc2[0] = (f32x4)(0.f); acc2[1] = (f32x4)(0.f);
#pragma unroll
    for (int s = 0; s < 4; ++s)
#pragma unroll
        for (int t = 0; t < 2; ++t) {
            const int orow = wave * 32 + t * 16 + lr;
            bf16x8 b = *(const bf16x8*)(A.wv2 + orow * 128 + s * 32 + lq * 8);
            acc2[t] = __builtin_amdgcn_mfma_f32_16x16x32_bf16(a[s], b, acc2[t], 0, 0, 0);
        }
    float dot[4] = {0.f, 0.f, 0.f, 0.f};
#pragma unroll
    for (int t = 0; t < 2; ++t) {
        const int col = wave * 32 + t * 16 + lr;
        const float bb = A.vb2[col], w3c = A.vw3[col];
#pragma unroll
        for (int r = 0; r < 4; ++r) {
            float v = acc2[t][r] + bb; v = v > 0.f ? v : 0.f;
            dot[r] += v * w3c;
        }
    }
#pragma unroll
    for (int r = 0; r < 4; ++r)
#pragma unroll
        for (int m = 1; m <= 8; m <<= 1) dot[r] += __shfl_xor(dot[r], m);
    if (lr == 0) {
#pragma unroll
        for (int r = 0; r < 4; ++r) sdot[wave * 16 + lq * 4 + r] = dot[r];
    }
    __syncthreads();
    if (wave == 0) {
        const int batch = r0 / N;
        const int rin = r0 - batch * N + lr;     // lr indexes the 16 rows
        float s = sdot[lr] + sdot[16 + lr] + sdot[32 + lr] + sdot[48 + lr];
        float val = (s + A.vb3[0]) * A.mask[batch * N + rin];
#pragma unroll
        for (int m = 1; m <= 8; m <<= 1) val += __shfl_xor(val, m);
        if (lane == 0) atomicAdd(&A.logit[batch], val);
    }
    __syncthreads();
}

// ---- gates+LSTM+LN on one 16-row tile; msgp/hb/cb -> hb, cb, ebt ----------------------
__device__ __forceinline__ void gates_tile(const UberArgs& A, int tile,
                                           unsigned short (*ebt)[136], float* sred)
{
    const int tid = threadIdx.x;
    const int lane = tid & 63, wave = tid >> 6;
    const int lr = lane & 15, lq = lane >> 4;
    const int r0 = tile * 16;
    const long long BNH = A.BNH;

    f32x4 acc[8];    // tt = gate*2 + half
#pragma unroll
    for (int t = 0; t < 8; ++t) acc[t] = (f32x4)(0.f);

    bf16x8 a[4];
#pragma unroll
    for (int s = 0; s < 4; ++s) {
        const long long base = (long long)(r0 + lr) * 128 + s * 32 + lq * 8;
        float v[8];
        bf16x8 t0 = *(const bf16x8*)(A.msgp + base);
#pragma unroll
        for (int e = 0; e < 8; ++e) v[e] = bf2f((unsigned short)t0[e]);
#pragma unroll
        for (int j = 1; j < 4; ++j) {
            bf16x8 tj = *(const bf16x8*)(A.msgp + (long long)j * BNH + base);
#pragma unroll
            for (int e = 0; e < 8; ++e) v[e] += bf2f((unsigned short)tj[e]);
        }
        bf16x8 r8;
#pragma unroll
        for (int e = 0; e < 8; ++e) r8[e] = (short)f2bf(v[e]);
        a[s] = r8;
    }
#pragma unroll
    for (int s = 0; s < 4; ++s)
#pragma unroll
        for (int tt = 0; tt < 8; ++tt) {
            const int brow = (tt >> 1) * 128 + wave * 32 + (tt & 1) * 16 + lr;
            bf16x8 b = *(const bf16x8*)(A.wih_b + brow * 128 + s * 32 + lq * 8);
            acc[tt] = __builtin_amdgcn_mfma_f32_16x16x32_bf16(a[s], b, acc[tt], 0, 0, 0);
        }
#pragma unroll
    for (int s = 0; s < 4; ++s)
        a[s] = *(const bf16x8*)(A.hb + (long long)(r0 + lr) * 128 + s * 32 + lq * 8);
#pragma unroll
    for (int s = 0; s < 4; ++s)
#pragma unroll
        for (int tt = 0; tt < 8; ++tt) {
            const int brow = (tt >> 1) * 128 + wave * 32 + (tt & 1) * 16 + lr;
            bf16x8 b = *(const bf16x8*)(A.whh_b + brow * 128 + s * 32 + lq * 8);
            acc[tt] = __builtin_amdgcn_mfma_f32_16x16x32_bf16(a[s], b, acc[tt], 0, 0, 0);
        }

    float hn[2][4];
    float4* cw = (float4*)A.cb;
#pragma unroll
    for (int half = 0; half < 2; ++half) {
        const int col = wave * 32 + half * 16 + lr;
        const float bi  = A.bih[col]       + A.bhh[col];
        const float bf_ = A.bih[col + 128] + A.bhh[col + 128];
        const float bg  = A.bih[col + 256] + A.bhh[col + 256];
        const float bo  = A.bih[col + 384] + A.bhh[col + 384];
        const long long cidx = ((long long)tile * 8 + wave * 2 + half) * 64 + lane;
        float4 cold = cw[cidx];
        float co[4] = {cold.x, cold.y, cold.z, cold.w};
        float cn[4];
#pragma unroll
        for (int r = 0; r < 4; ++r) {
            float iv = acc[0 + half][r] + bi;
            float fv = acc[2 + half][r] + bf_;
            float gv = acc[4 + half][r] + bg;
            float ov = acc[6 + half][r] + bo;
            float cc = sigf(fv) * co[r] + sigf(iv) * tanhf(gv);
            cn[r] = cc;
            hn[half][r] = sigf(ov) * tanhf(cc);
        }
        cw[cidx] = make_float4(cn[0], cn[1], cn[2], cn[3]);
    }

    float ps1[4], ps2[4];
#pragma unroll
    for (int r = 0; r < 4; ++r) {
        float s1 = hn[0][r] + hn[1][r];
        float s2 = hn[0][r] * hn[0][r] + hn[1][r] * hn[1][r];
#pragma unroll
        for (int m = 1; m <= 8; m <<= 1) {
            s1 += __shfl_xor(s1, m);
            s2 += __shfl_xor(s2, m);
        }
        ps1[r] = s1; ps2[r] = s2;
    }
    if (lr == 0) {
#pragma unroll
        for (int r = 0; r < 4; ++r) {
            sred[(wave * 16 + lq * 4 + r) * 2 + 0] = ps1[r];
            sred[(wave * 16 + lq * 4 + r) * 2 + 1] = ps2[r];
        }
    }
    __syncthreads();

#pragma unroll
    for (int half = 0; half < 2; ++half) {
        const int col = wave * 32 + half * 16 + lr;
        const float g = A.lng[col], bb = A.lnb[col];
#pragma unroll
        for (int r = 0; r < 4; ++r) {
            const int row = lq * 4 + r;
            float S1 = sred[(row) * 2] + sred[(16 + row) * 2] + sred[(32 + row) * 2] + sred[(48 + row) * 2];
            float S2 = sred[(row) * 2 + 1] + sred[(16 + row) * 2 + 1] + sred[(32 + row) * 2 + 1] + sred[(48 + row) * 2 + 1];
            float mean = S1 * (1.f / 128.f);
            float var  = S2 * (1.f / 128.f) - mean * mean;
            float rs = rsqrtf(var + LN_EPS);
            A.hb[(long long)(r0 + row) * 128 + col] = f2bf(hn[half][r]);
            ebt[row][col] = f2bf((hn[half][r] - mean) * rs * g + bb);
        }
    }
}

// ---- fp8 aggregation phase: single-buffer BK=128, 32 KB LDS ---------------------------
__device__ void agg_phase(const UberArgs& A, char* smem)
{
    unsigned char* sA = (unsigned char*)smem;            // 16 KB
    unsigned char* sB = (unsigned char*)smem + 16384;    // 16 KB

    const int tid = threadIdx.x;
    const int lane = tid & 63, w = tid >> 6;
    const int lr = lane & 15, lq = lane >> 4;
    const int wr = w & 1, wc = w >> 1;
    const int N = A.N;
    const int nrt = N >> 7;              // 32
    const int bid = blockIdx.x;
    const int xt    = bid % nrt;
    const int ksp   = (bid / nrt) & 3;
    const int batch = bid / (nrt * 4);
    const int r0 = xt * 128;
    const int kbase = ksp * (N >> 2);
    const int nsteps = (N >> 2) >> 7;

    const unsigned char* xrow = A.x8 + (long long)batch * N * N;
    const unsigned char* mrow = A.m8 + (long long)batch * 128 * N;

    f32x4 acc[4][4];
#pragma unroll
    for (int tr = 0; tr < 4; ++tr)
#pragma unroll
        for (int tn = 0; tn < 4; ++tn) acc[tr][tn] = (f32x4)(0.f);

    for (int step = 0; step < nsteps; ++step) {
        const int k0 = kbase + step * 128;
        // stage (swizzled global source, linear LDS dest — rule #21)
#pragma unroll
        for (int j = 0; j < 4; ++j) {
            const int c = ((w * 4 + j) << 6) + lane;
            const int row = c >> 3;
            const int gs = (c & 7) ^ (row & 7);
            gload_lds16(xrow + (long long)(r0 + row) * N + k0 + gs * 16,
                        sA + (w * 4 + j) * 1024);
        }
#pragma unroll
        for (int j = 0; j < 4; ++j) {
            const int c = ((w * 4 + j) << 6) + lane;
            const int row = c >> 3;
            const int gs = (c & 7) ^ (row & 7);
            gload_lds16(mrow + (long long)row * N + k0 + gs * 16,
                        sB + (w * 4 + j) * 1024);
        }
        __syncthreads();     // compiler drains vmcnt before s_barrier
#pragma unroll
        for (int ks = 0; ks < 4; ++ks) {
            const int g    = ks * 4 + lq;
            const int half = (g & 1) << 3;
            const int s16  = g >> 1;
            long af[4], bfr[4];
#pragma unroll
            for (int tr = 0; tr < 4; ++tr) {
                const int row = wr * 64 + tr * 16 + lr;
                af[tr] = *(const long*)(sA + row * 128 + ((s16 ^ (row & 7)) << 4) + half);
            }
#pragma unroll
            for (int tn = 0; tn < 4; ++tn) {
                const int row = wc * 64 + tn * 16 + lr;
                bfr[tn] = *(const long*)(sB + row * 128 + ((s16 ^ (row & 7)) << 4) + half);
            }
#pragma unroll
            for (int tr = 0; tr < 4; ++tr)
#pragma unroll
                for (int tn = 0; tn < 4; ++tn)
                    acc[tr][tn] = __builtin_amdgcn_mfma_f32_16x16x32_fp8_fp8(
                        af[tr], bfr[tn], acc[tr][tn], 0, 0, 0);
        }
        __syncthreads();
    }

    unsigned short* outb = A.msgp + (long long)ksp * A.BNH + (long long)(batch * N + r0) * 128;
#pragma unroll
    for (int tr = 0; tr < 4; ++tr)
#pragma unroll
        for (int tn = 0; tn < 4; ++tn)
#pragma unroll
            for (int r = 0; r < 4; ++r)
                outb[(long long)(wr * 64 + tr * 16 + lq * 4 + r) * 128 + wc * 64 + tn * 16 + lr]
                    = f2bf(acc[tr][tn][r]);
}

// ---- phase 1: hb broadcast + msg on initial embed -------------------------------------
__device__ void phase1(const UberArgs& A, char* smem)
{
    const int tid = threadIdx.x;
    const long long gtid = (long long)blockIdx.x * NT + tid;
    const long long GT = (long long)NB * NT;
    const long long NH = (long long)A.N * 128;

    const long long n4 = A.BNH >> 2;
    for (long long i = gtid; i < n4; i += GT) {
        const long long idx = i * 4;
        const int b = (int)(idx / NH);
        const int j = (int)(idx & 127);
        ushort4 o;
        o.x = f2bf(A.init0[b * 128 + j]);
        o.y = f2bf(A.init0[b * 128 + j + 1]);
        o.z = f2bf(A.init0[b * 128 + j + 2]);
        o.w = f2bf(A.init0[b * 128 + j + 3]);
        ((ushort4*)A.hb)[i] = o;
    }

    unsigned short (*ebt)[136] = (unsigned short(*)[136])smem;
    unsigned short (*act)[136] = (unsigned short(*)[136])(smem + 4352);
    const int ntiles = (A.B * A.N) / 16;
    for (int pass = 0; pass < ntiles / NB; ++pass) {
        const int tile = blockIdx.x + pass * NB;
        const int batch = (tile * 16) / A.N;
        __syncthreads();
        for (int i = tid; i < 16 * 128; i += NT) {
            const int row = i >> 7, col = i & 127;
            ebt[row][col] = f2bf(A.embed0[batch * 128 + col]);
        }
        __syncthreads();
        msg_tile(A, tile, ebt, act);
        __syncthreads();
    }
}

__device__ void g_phase(const UberArgs& A, char* smem, bool do_vote)
{
    unsigned short (*ebt)[136] = (unsigned short(*)[136])smem;
    unsigned short (*act)[136] = (unsigned short(*)[136])(smem + 4352);
    float* sred = (float*)(smem + 8704);
    float* sdot = (float*)(smem + 9472);
    const int ntiles = (A.B * A.N) / 16;
    for (int pass = 0; pass < ntiles / NB; ++pass) {
        const int tile = blockIdx.x + pass * NB;
        __syncthreads();
        gates_tile(A, tile, ebt, sred);
        __syncthreads();
        if (do_vote) vote_tile(A, tile, ebt, act, sdot);
        else         msg_tile(A, tile, ebt, act);
        __syncthreads();
    }
}

__global__ __launch_bounds__(NT, 2)
void uber_kernel(UberArgs A)
{
    __shared__ __align__(16) char smem[32768];
    cg::grid_group grid = cg::this_grid();

    prologue(A, smem);
    __threadfence(); grid.sync();
    phase1(A, smem);
    __threadfence(); grid.sync();
    for (int it = 0; it < A.iters; ++it) {
        agg_phase(A, smem);
        __threadfence(); grid.sync();
        g_phase(A, smem, it == A.iters - 1);
        __threadfence(); grid.sync();
    }
    if (blockIdx.x == 0 && threadIdx.x < (unsigned)A.B)
        A.out[threadIdx.x] = sigf(A.logit[threadIdx.x]);
}

// ===================== fallback path (round-1 kernels, verified) =======================
__device__ __forceinline__ void layer128(const unsigned short* __restrict__ W,
                                         const bf16x8 a[4], f32x4 acc[8],
                                         int lr, int lq)
{
#pragma unroll
    for (int s = 0; s < 4; ++s) {
#pragma unroll
        for (int tn = 0; tn < 8; ++tn) {
            bf16x8 b = *(const bf16x8*)(W + (tn * 16 + lr) * 128 + s * 32 + lq * 8);
            acc[tn] = __builtin_amdgcn_mfma_f32_16x16x32_bf16(a[s], b, acc[tn], 0, 0, 0);
        }
    }
}

template<bool FP8>
__global__ __launch_bounds__(256)
void msg_mlp_kernel(const unsigned short* __restrict__ embed,
                    const unsigned short* __restrict__ w1, const float* __restrict__ b1,
                    const unsigned short* __restrict__ w2, const float* __restrict__ b2,
                    const unsigned short* __restrict__ w3, const float* __restrict__ b3,
                    unsigned short* __restrict__ m_t, unsigned char* __restrict__ m8,
                    int N)
{
    __shared__ unsigned short sact[4][16][136];
    const int lane = threadIdx.x & 63, wave = threadIdx.x >> 6;
    const int lr = lane & 15, lq = lane >> 4;
    const int r0 = (blockIdx.x * 4 + wave) * 16;

    bf16x8 a[4];
    f32x4 acc[8];

#pragma unroll
    for (int s = 0; s < 4; ++s)
        a[s] = *(const bf16x8*)(embed + (long long)(r0 + lr) * 128 + s * 32 + lq * 8);
#pragma unroll
    for (int tn = 0; tn < 8; ++tn) acc[tn] = (f32x4)(0.f);
    layer128(w1, a, acc, lr, lq);

#pragma unroll
    for (int tn = 0; tn < 8; ++tn) {
        float bb = b1[tn * 16 + lr];
#pragma unroll
        for (int r = 0; r < 4; ++r) {
            float v = acc[tn][r] + bb; v = v > 0.f ? v : 0.f;
            sact[wave][lq * 4 + r][tn * 16 + lr] = f2bf(v);
        }
    }
    __syncthreads();
#pragma unroll
    for (int s = 0; s < 4; ++s)
        a[s] = *(const bf16x8*)&sact[wave][lr][s * 32 + lq * 8];
#pragma unroll
    for (int tn = 0; tn < 8; ++tn) acc[tn] = (f32x4)(0.f);
    layer128(w2, a, acc, lr, lq);

#pragma unroll
    for (int tn = 0; tn < 8; ++tn) {
        float bb = b2[tn * 16 + lr];
#pragma unroll
        for (int r = 0; r < 4; ++r) {
            float v = acc[tn][r] + bb; v = v > 0.f ? v : 0.f;
            sact[wave][lq * 4 + r][tn * 16 + lr] = f2bf(v);
        }
    }
    __syncthreads();
#pragma unroll
    for (int s = 0; s < 4; ++s)
        a[s] = *(const bf16x8*)&sact[wave][lr][s * 32 + lq * 8];
#pragma unroll
    for (int tn = 0; tn < 8; ++tn) acc[tn] = (f32x4)(0.f);
    layer128(w3, a, acc, lr, lq);

    const int batch = r0 / N;
    const int rin0 = r0 - batch * N + lq * 4;
#pragma unroll
    for (int tn = 0; tn < 8; ++tn) {
        float bb = b3[tn * 16 + lr];
        float v0 = acc[tn][0] + bb, v1 = acc[tn][1] + bb;
        float v2 = acc[tn][2] + bb, v3 = acc[tn][3] + bb;
        if constexpr (FP8) {
            int pk = __builtin_amdgcn_cvt_pk_fp8_f32(v0, v1, 0, false);
            pk = __builtin_amdgcn_cvt_pk_fp8_f32(v2, v3, pk, true);
            *(unsigned int*)(m8 + (long long)(batch * 128 + tn * 16 + lr) * N + rin0) = (unsigned)pk;
        } else {
            ushort4 o;
            o.x = f2bf(v0); o.y = f2bf(v1); o.z = f2bf(v2); o.w = f2bf(v3);
            *(ushort4*)(m_t + ((long long)(batch * 128 + tn * 16 + lr)) * N + rin0) = o;
        }
    }
}

__global__ __launch_bounds__(256)
void agg_fp8_kernel(const unsigned char* __restrict__ x8,
                    const unsigned char* __restrict__ m8,
                    unsigned short* __restrict__ msgp, int N, long long BNH)
{
    __shared__ unsigned char sA[2][128 * 128];
    __shared__ unsigned char sB[2][128 * 128];

    const int tid = threadIdx.x;
    const int lane = tid & 63, w = tid >> 6;
    const int lr = lane & 15, lq = lane >> 4;
    const int wr = w & 1, wc = w >> 1;
    const int r0 = blockIdx.x * 128;
    const int ksp = blockIdx.y;
    const int batch = blockIdx.z;
    const int kbase = ksp * (N >> 2);
    const int nsteps = (N >> 2) >> 7;

    const unsigned char* xrow = x8 + (long long)batch * N * N;
    const unsigned char* mrow = m8 + (long long)batch * 128 * N;

    f32x4 acc[4][4];
#pragma unroll
    for (int tr = 0; tr < 4; ++tr)
#pragma unroll
        for (int tn = 0; tn < 4; ++tn) acc[tr][tn] = (f32x4)(0.f);

    auto stage = [&](int b, int step) {
        const int k0 = kbase + step * 128;
#pragma unroll
        for (int j = 0; j < 4; ++j) {
            const int c = ((w * 4 + j) << 6) + lane;
            const int row = c >> 3;
            const int gs = (c & 7) ^ (row & 7);
            gload_lds16(xrow + (long long)(r0 + row) * N + k0 + gs * 16,
                        (char*)sA[b] + (w * 4 + j) * 1024);
        }
#pragma unroll
        for (int j = 0; j < 4; ++j) {
            const int c = ((w * 4 + j) << 6) + lane;
            const int row = c >> 3;
            const int gs = (c & 7) ^ (row & 7);
            gload_lds16(mrow + (long long)row * N + k0 + gs * 16,
                        (char*)sB[b] + (w * 4 + j) * 1024);
        }
    };

    stage(0, 0);
    __syncthreads();
    int buf = 0;
    for (int step = 0; step < nsteps; ++step) {
        if (step + 1 < nsteps) stage(buf ^ 1, step + 1);
        const unsigned char* Ab = sA[buf];
        const unsigned char* Bb = sB[buf];
#pragma unroll
        for (int ks = 0; ks < 4; ++ks) {
            const int g    = ks * 4 + lq;
            const int half = (g & 1) << 3;
            const int s16  = g >> 1;
            long af[4], bfr[4];
#pragma unroll
            for (int tr = 0; tr < 4; ++tr) {
                const int row = wr * 64 + tr * 16 + lr;
                af[tr] = *(const long*)(Ab + row * 128 + ((s16 ^ (row & 7)) << 4) + half);
            }
#pragma unroll
            for (int tn = 0; tn < 4; ++tn) {
                const int row = wc * 64 + tn * 16 + lr;
                bfr[tn] = *(const long*)(Bb + row * 128 + ((s16 ^ (row & 7)) << 4) + half);
            }
#pragma unroll
            for (int tr = 0; tr < 4; ++tr)
#pragma unroll
                for (int tn = 0; tn < 4; ++tn)
                    acc[tr][tn] = __builtin_amdgcn_mfma_f32_16x16x32_fp8_fp8(
                        af[tr], bfr[tn], acc[tr][tn], 0, 0, 0);
        }
        __syncthreads();
        buf ^= 1;
    }

    unsigned short* outb = msgp + (long long)ksp * BNH + (long long)(batch * N + r0) * 128;
#pragma unroll
    for (int tr = 0; tr < 4; ++tr)
#pragma unroll
        for (int tn = 0; tn < 4; ++tn)
#pragma unroll
            for (int r = 0; r < 4; ++r)
                outb[(long long)(wr * 64 + tr * 16 + lq * 4 + r) * 128 + wc * 64 + tn * 16 + lr]
                    = f2bf(acc[tr][tn][r]);
}

__global__ __launch_bounds__(256)
void agg_fallback_kernel(const float* __restrict__ xf,
                         const unsigned short* __restrict__ mt, float* __restrict__ msgp0,
                         int N)
{
    __shared__ float sacc[4][16][132];
    const int lane = threadIdx.x & 63, wave = threadIdx.x >> 6;
    const int lr = lane & 15, lq = lane >> 4;
    const int batch = blockIdx.y;
    const int rowBase = blockIdx.x * 16;
    const int kBase = wave * (N >> 2);
    const int kIters = N >> 7;

    const float* af = xf + (long long)batch * N * N + (long long)(rowBase + lr) * N + kBase + lq * 8;
    const long long bbase = (long long)batch * 128 * N + (long long)lr * N + kBase + lq * 8;

    f32x4 acc[8];
#pragma unroll
    for (int tn = 0; tn < 8; ++tn) acc[tn] = (f32x4)(0.f);

    for (int it = 0; it < kIters; ++it) {
        const int k = it * 32;
        float4 lo = *(const float4*)(af + k);
        float4 hi = *(const float4*)(af + k + 4);
        bf16x8 a0;
        a0[0] = (short)f2bf(lo.x); a0[1] = (short)f2bf(lo.y);
        a0[2] = (short)f2bf(lo.z); a0[3] = (short)f2bf(lo.w);
        a0[4] = (short)f2bf(hi.x); a0[5] = (short)f2bf(hi.y);
        a0[6] = (short)f2bf(hi.z); a0[7] = (short)f2bf(hi.w);
#pragma unroll
        for (int tn = 0; tn < 8; ++tn) {
            bf16x8 b0 = *(const bf16x8*)(mt + bbase + (long long)tn * 16 * N + k);
            acc[tn] = __builtin_amdgcn_mfma_f32_16x16x32_bf16(a0, b0, acc[tn], 0, 0, 0);
        }
    }

#pragma unroll
    for (int tn = 0; tn < 8; ++tn)
#pragma unroll
        for (int r = 0; r < 4; ++r)
            sacc[wave][lq * 4 + r][tn * 16 + lr] = acc[tn][r];
    __syncthreads();
    {
        const int t = threadIdx.x;
        const int row = t >> 4, cb2 = (t & 15) * 8;
        float o[8];
#pragma unroll
        for (int j = 0; j < 8; ++j)
            o[j] = sacc[0][row][cb2 + j] + sacc[1][row][cb2 + j]
                 + sacc[2][row][cb2 + j] + sacc[3][row][cb2 + j];
        float* dst = msgp0 + (long long)(batch * N + rowBase + row) * 128 + cb2;
        *(float4*)dst = make_float4(o[0], o[1], o[2], o[3]);
        *(float4*)(dst + 4) = make_float4(o[4], o[5], o[6], o[7]);
    }
}

template<int NPART, bool BF16P>
__global__ __launch_bounds__(256)
void gates_lstm_kernel(const void* __restrict__ msgp, long long BNH,
                       unsigned short* hb, float* cb,
                       const unsigned short* __restrict__ wih,
                       const unsigned short* __restrict__ whh,
                       const float* __restrict__ bih, const float* __restrict__ bhh,
                       const float* __restrict__ lng, const float* __restrict__ lnb,
                       unsigned short* __restrict__ embed_out)
{
    __shared__ float sred[4][16][2];
    const int lane = threadIdx.x & 63, wave = threadIdx.x >> 6;
    const int lr = lane & 15, lq = lane >> 4;
    const int r0 = blockIdx.x * 16;

    f32x4 acc[8];
#pragma unroll
    for (int t = 0; t < 8; ++t) acc[t] = (f32x4)(0.f);

    bf16x8 a[4];
#pragma unroll
    for (int s = 0; s < 4; ++s) {
        const long long base = (long long)(r0 + lr) * 128 + s * 32 + lq * 8;
        float v[8];
        if constexpr (BF16P) {
            const unsigned short* mp = (const unsigned short*)msgp;
            bf16x8 t0 = *(const bf16x8*)(mp + base);
#pragma unroll
            for (int e = 0; e < 8; ++e) v[e] = bf2f((unsigned short)t0[e]);
#pragma unroll
            for (int j = 1; j < NPART; ++j) {
                bf16x8 tj = *(const bf16x8*)(mp + (long long)j * BNH + base);
#pragma unroll
                for (int e = 0; e < 8; ++e) v[e] += bf2f((unsigned short)tj[e]);
            }
        } else {
            const float* mp = (const float*)msgp;
            float4 t0 = *(const float4*)(mp + base);
            float4 t1 = *(const float4*)(mp + base + 4);
            v[0] = t0.x; v[1] = t0.y; v[2] = t0.z; v[3] = t0.w;
            v[4] = t1.x; v[5] = t1.y; v[6] = t1.z; v[7] = t1.w;
#pragma unroll
            for (int j = 1; j < NPART; ++j) {
                float4 u0 = *(const float4*)(mp + (long long)j * BNH + base);
                float4 u1 = *(const float4*)(mp + (long long)j * BNH + base + 4);
                v[0] += u0.x; v[1] += u0.y; v[2] += u0.z; v[3] += u0.w;
                v[4] += u1.x; v[5] += u1.y; v[6] += u1.z; v[7] += u1.w;
            }
        }
        bf16x8 r8;
#pragma unroll
        for (int e = 0; e < 8; ++e) r8[e] = (short)f2bf(v[e]);
        a[s] = r8;
    }
#pragma unroll
    for (int s = 0; s < 4; ++s)
#pragma unroll
        for (int tt = 0; tt < 8; ++tt) {
            const int brow = (tt >> 1) * 128 + wave * 32 + (tt & 1) * 16 + lr;
            bf16x8 b = *(const bf16x8*)(wih + brow * 128 + s * 32 + lq * 8);
            acc[tt] = __builtin_amdgcn_mfma_f32_16x16x32_bf16(a[s], b, acc[tt], 0, 0, 0);
        }
#pragma unroll
    for (int s = 0; s < 4; ++s)
        a[s] = *(const bf16x8*)((const unsigned short*)hb + (long long)(r0 + lr) * 128 + s * 32 + lq * 8);
#pragma unroll
    for (int s = 0; s < 4; ++s)
#pragma unroll
        for (int tt = 0; tt < 8; ++tt) {
            const int brow = (tt >> 1) * 128 + wave * 32 + (tt & 1) * 16 + lr;
            bf16x8 b = *(const bf16x8*)(whh + brow * 128 + s * 32 + lq * 8);
            acc[tt] = __builtin_amdgcn_mfma_f32_16x16x32_bf16(a[s], b, acc[tt], 0, 0, 0);
        }

    float hn[2][4];
    float4* cw = (float4*)cb;
#pragma unroll
    for (int half = 0; half < 2; ++half) {
        const int col = wave * 32 + half * 16 + lr;
        const float bi  = bih[col]       + bhh[col];
        const float bf_ = bih[col + 128] + bhh[col + 128];
        const float bg  = bih[col + 256] + bhh[col + 256];
        const float bo  = bih[col + 384] + bhh[col + 384];
        const long long cidx = ((long long)blockIdx.x * 8 + wave * 2 + half) * 64 + lane;
        float4 cold = cw[cidx];
        float co[4] = {cold.x, cold.y, cold.z, cold.w};
        float cn[4];
#pragma unroll
        for (int r = 0; r < 4; ++r) {
            float iv = acc[0 + half][r] + bi;
            float fv = acc[2 + half][r] + bf_;
            float gv = acc[4 + half][r] + bg;
            float ov = acc[6 + half][r] + bo;
            float cc = sigf(fv) * co[r] + sigf(iv) * tanhf(gv);
            cn[r] = cc;
            hn[half][r] = sigf(ov) * tanhf(cc);
        }
        cw[cidx] = make_float4(cn[0], cn[1], cn[2], cn[3]);
    }

    float ps1[4], ps2[4];
#pragma unroll
    for (int r = 0; r < 4; ++r) {
        float s1 = hn[0][r] + hn[1][r];
        float s2 = hn[0][r] * hn[0][r] + hn[1][r] * hn[1][r];
#pragma unroll
        for (int m = 1; m <= 8; m <<= 1) {
            s1 += __shfl_xor(s1, m);
            s2 += __shfl_xor(s2, m);
        }
        ps1[r] = s1; ps2[r] = s2;
    }
    if (lr == 0) {
#pragma unroll
        for (int r = 0; r < 4; ++r) {
            sred[wave][lq * 4 + r][0] = ps1[r];
            sred[wave][lq * 4 + r][1] = ps2[r];
        }
    }
    __syncthreads();

#pragma unroll
    for (int half = 0; half < 2; ++half) {
        const int col = wave * 32 + half * 16 + lr;
        const float g = lng[col], bb = lnb[col];
#pragma unroll
        for (int r = 0; r < 4; ++r) {
            const int row = lq * 4 + r;
            float S1 = sred[0][row][0] + sred[1][row][0] + sred[2][row][0] + sred[3][row][0];
            float S2 = sred[0][row][1] + sred[1][row][1] + sred[2][row][1] + sred[3][row][1];
            float mean = S1 * (1.f / 128.f);
            float var  = S2 * (1.f / 128.f) - mean * mean;
            float rs = rsqrtf(var + LN_EPS);
            long long off = (long long)(r0 + row) * 128 + col;
            hb[off] = f2bf(hn[half][r]);
            embed_out[off] = f2bf((hn[half][r] - mean) * rs * g + bb);
        }
    }
}

__global__ __launch_bounds__(256)
void vote_mlp_kernel(const unsigned short* __restrict__ embed,
                     const unsigned short* __restrict__ w1, const float* __restrict__ b1,
                     const unsigned short* __restrict__ w2, const float* __restrict__ b2,
                     const float* __restrict__ w3, const float* __restrict__ b3p,
                     const float* __restrict__ mask, float* __restrict__ logit, int N)
{
    __shared__ unsigned short sact[4][16][136];
    const int lane = threadIdx.x & 63, wave = threadIdx.x >> 6;
    const int lr = lane & 15, lq = lane >> 4;
    const int r0 = (blockIdx.x * 4 + wave) * 16;

    bf16x8 a[4];
    f32x4 acc[8];
#pragma unroll
    for (int s = 0; s < 4; ++s)
        a[s] = *(const bf16x8*)(embed + (long long)(r0 + lr) * 128 + s * 32 + lq * 8);
#pragma unroll
    for (int tn = 0; tn < 8; ++tn) acc[tn] = (f32x4)(0.f);
    layer128(w1, a, acc, lr, lq);

#pragma unroll
    for (int tn = 0; tn < 8; ++tn) {
        float bb = b1[tn * 16 + lr];
#pragma unroll
        for (int r = 0; r < 4; ++r) {
            float v = acc[tn][r] + bb; v = v > 0.f ? v : 0.f;
            sact[wave][lq * 4 + r][tn * 16 + lr] = f2bf(v);
        }
    }
    __syncthreads();
#pragma unroll
    for (int s = 0; s < 4; ++s)
        a[s] = *(const bf16x8*)&sact[wave][lr][s * 32 + lq * 8];
#pragma unroll
    for (int tn = 0; tn < 8; ++tn) acc[tn] = (f32x4)(0.f);
    layer128(w2, a, acc, lr, lq);

    float dot[4] = {0.f, 0.f, 0.f, 0.f};
#pragma unroll
    for (int tn = 0; tn < 8; ++tn) {
        const int col = tn * 16 + lr;
        const float bb = b2[col], w3c = w3[col];
#pragma unroll
        for (int r = 0; r < 4; ++r) {
            float v = acc[tn][r] + bb; v = v > 0.f ? v : 0.f;
            dot[r] += v * w3c;
        }
    }
#pragma unroll
    for (int r = 0; r < 4; ++r)
#pragma unroll
        for (int m = 1; m <= 8; m <<= 1) dot[r] += __shfl_xor(dot[r], m);

    const int batch = r0 / N;
    const float b3 = b3p[0];
    const int base = r0 + lq * 4;
    float wsum = mask[base + 0] * (dot[0] + b3) + mask[base + 1] * (dot[1] + b3)
               + mask[base + 2] * (dot[2] + b3) + mask[base + 3] * (dot[3] + b3);
    float t = (lr == 0) ? wsum : 0.f;
    t += __shfl_xor(t, 16);
    t += __shfl_xor(t, 32);
    if (lane == 0) atomicAdd(&logit[batch], t);
}

__global__ __launch_bounds__(128)
void init_kernel(const float* __restrict__ kk, const float* __restrict__ nn,
                 const float* __restrict__ w1, const float* __restrict__ b1,
                 const float* __restrict__ w2, const float* __restrict__ b2,
                 const float* __restrict__ w3, const float* __restrict__ b3,
                 const float* __restrict__ lng, const float* __restrict__ lnb,
                 float* __restrict__ init0, float* __restrict__ embed0,
                 float* __restrict__ logit, int H)
{
    int b = blockIdx.x, j = threadIdx.x;
    __shared__ float s1[128];
    __shared__ float s2[128];
    __shared__ float red[128];
    if (j == 0) logit[b] = 0.f;
    float kv = kk[b], nv = nn[b];
    float h1 = w1[j * 2 + 0] * kv + w1[j * 2 + 1] * nv + b1[j];
    h1 = h1 > 0.f ? h1 : 0.f;
    s1[j] = h1; __syncthreads();
    float h2 = b2[j];
    for (int q = 0; q < H; ++q) h2 += w2[j * H + q] * s1[q];
    h2 = h2 > 0.f ? h2 : 0.f;
    s2[j] = h2; __syncthreads();
    float o = b3[j];
    for (int q = 0; q < H; ++q) o += w3[j * H + q] * s2[q];
    init0[b * H + j] = o;

    red[j] = o; __syncthreads();
    for (int s = 64; s > 0; s >>= 1) { if (j < s) red[j] += red[j + s]; __syncthreads(); }
    float mu = red[0] / (float)H;
    __syncthreads();
    float d = o - mu;
    red[j] = d * d; __syncthreads();
    for (int s = 64; s > 0; s >>= 1) { if (j < s) red[j] += red[j + s]; __syncthreads(); }
    float var = red[0] / (float)H;
    embed0[b * H + j] = d * rsqrtf(var + LN_EPS) * lng[j] + lnb[j];
}

__global__ void bcast_kernel(const float* __restrict__ init0, const float* __restrict__ embed0,
                             unsigned short* __restrict__ hb, float* __restrict__ cb,
                             unsigned short* __restrict__ embed,
                             long long total, long long NH)
{
    long long idx = (long long)blockIdx.x * blockDim.x + threadIdx.x;
    if (idx >= total) return;
    int b = (int)(idx / NH);
    int j = (int)(idx & 127);
    hb[idx] = f2bf(init0[b * 128 + j]);
    embed[idx] = f2bf(embed0[b * 128 + j]);
    cb[idx] = 0.f;
}

__global__ void cast8_kernel(const float* __restrict__ x, unsigned char* __restrict__ x8,
                             long long n8)
{
    long long i = ((long long)blockIdx.x * blockDim.x + threadIdx.x);
    if (i >= n8) return;
    const float* s = x + i * 8;
    float4 a = *(const float4*)s;
    float4 b = *(const float4*)(s + 4);
    int lo = __builtin_amdgcn_cvt_pk_fp8_f32(a.x, a.y, 0, false);
    lo = __builtin_amdgcn_cvt_pk_fp8_f32(a.z, a.w, lo, true);
    int hi = __builtin_amdgcn_cvt_pk_fp8_f32(b.x, b.y, 0, false);
    hi = __builtin_amdgcn_cvt_pk_fp8_f32(b.z, b.w, hi, true);
    int2 o; o.x = lo; o.y = hi;
    *(int2*)(x8 + i * 8) = o;
}

struct CastArgs {
    const float* src[7];
    unsigned short* dst[7];
    int n[7];
};

__global__ void castw_kernel(CastArgs a)
{
    int rg = blockIdx.y;
    int i = (blockIdx.x * blockDim.x + threadIdx.x) * 4;
    if (i < a.n[rg]) {
        float4 v = *(const float4*)(a.src[rg] + i);
        ushort4 o;
        o.x = f2bf(v.x); o.y = f2bf(v.y); o.z = f2bf(v.z); o.w = f2bf(v.w);
        *(ushort4*)(a.dst[rg] + i) = o;
    }
}

__global__ void sigmoid_kernel(const float* __restrict__ logit, float* __restrict__ out, int B)
{
    int b = threadIdx.x;
    if (b < B) out[b] = 1.f / (1.f + __expf(-logit[b]));
}

// ---------------- launch ---------------------------------------------------------------
extern "C" void kernel_launch(void* const* d_in, const int* in_sizes, int n_in,
                              void* d_out, int out_size, void* d_ws, size_t ws_size,
                              hipStream_t stream)
{
    const float* x    = (const float*)d_in[0];
    const float* kk   = (const float*)d_in[1];
    const float* nn   = (const float*)d_in[2];
    const float* mask = (const float*)d_in[3];
    const float* iw1  = (const float*)d_in[4];
    const float* ib1  = (const float*)d_in[5];
    const float* iw2  = (const float*)d_in[6];
    const float* ib2  = (const float*)d_in[7];
    const float* iw3  = (const float*)d_in[8];
    const float* ib3  = (const float*)d_in[9];
    const float* mw1  = (const float*)d_in[10];
    const float* mb1  = (const float*)d_in[11];
    const float* mw2  = (const float*)d_in[12];
    const float* mb2  = (const float*)d_in[13];
    const float* mw3  = (const float*)d_in[14];
    const float* mb3  = (const float*)d_in[15];
    const float* wih  = (const float*)d_in[16];
    const float* whh  = (const float*)d_in[17];
    const float* bih  = (const float*)d_in[18];
    const float* bhh  = (const float*)d_in[19];
    const float* lng  = (const float*)d_in[20];
    const float* lnb  = (const float*)d_in[21];
    const float* vw1  = (const float*)d_in[22];
    const float* vb1  = (const float*)d_in[23];
    const float* vw2  = (const float*)d_in[24];
    const float* vb2  = (const float*)d_in[25];
    const float* vw3  = (const float*)d_in[26];
    const float* vb3  = (const float*)d_in[27];
    float* out = (float*)d_out;

    const int B = in_sizes[1];        // 4
    const int H = in_sizes[5];        // 128
    const int N = in_sizes[3] / B;    // 4096
    const long long NH  = (long long)N * H;
    const long long BNH = (long long)B * NH;
    const int M = B * N;

    char* p = (char*)d_ws;
    auto alloc = [&](long long bytes) {
        char* q = p; p += (bytes + 255) & ~255LL; return q;
    };
    float*          cb     = (float*)alloc(BNH * 4);
    unsigned short* embed  = (unsigned short*)alloc(BNH * 2);
    unsigned short* hb     = (unsigned short*)alloc(BNH * 2);
    unsigned short* m_t    = (unsigned short*)alloc(BNH * 2);
    unsigned short* msgp   = (unsigned short*)alloc(4 * BNH * 2);
    float*          init0  = (float*)alloc((long long)B * H * 4);
    float*          embed0 = (float*)alloc((long long)B * H * 4);
    float*          logit  = (float*)alloc((long long)B * 4);
    unsigned short* wb_m1  = (unsigned short*)alloc((long long)H * H * 2);
    unsigned short* wb_m2  = (unsigned short*)alloc((long long)H * H * 2);
    unsigned short* wb_m3  = (unsigned short*)alloc((long long)H * H * 2);
    unsigned short* wb_ih  = (unsigned short*)alloc(4LL * H * H * 2);
    unsigned short* wb_hh  = (unsigned short*)alloc(4LL * H * H * 2);
    unsigned short* wb_v1  = (unsigned short*)alloc((long long)H * H * 2);
    unsigned short* wb_v2  = (unsigned short*)alloc((long long)H * H * 2);
    unsigned char*  m8_t   = (unsigned char*)alloc(BNH);
    unsigned char*  x8     = (unsigned char*)alloc((long long)B * N * N);
    const bool ws_ok = ((long long)(p - (char*)d_ws) <= (long long)ws_size);
    const bool coop_shape = ws_ok && B == 4 && N == 4096 && H == 128;

    if (coop_shape) {
        UberArgs ua;
        ua.x = x; ua.kk = kk; ua.nn = nn; ua.mask = mask;
        ua.iw1 = iw1; ua.ib1 = ib1; ua.iw2 = iw2; ua.ib2 = ib2; ua.iw3 = iw3; ua.ib3 = ib3;
        ua.mw1 = mw1; ua.mb1 = mb1; ua.mw2 = mw2; ua.mb2 = mb2; ua.mw3 = mw3; ua.mb3 = mb3;
        ua.wih = wih; ua.whh = whh; ua.bih = bih; ua.bhh = bhh; ua.lng = lng; ua.lnb = lnb;
        ua.vw1 = vw1; ua.vb1 = vb1; ua.vw2 = vw2; ua.vb2 = vb2; ua.vw3 = vw3; ua.vb3 = vb3;
        ua.wm1 = wb_m1; ua.wm2 = wb_m2; ua.wm3 = wb_m3;
        ua.wih_b = wb_ih; ua.whh_b = wb_hh; ua.wv1 = wb_v1; ua.wv2 = wb_v2;
        ua.x8 = x8; ua.m8 = m8_t; ua.msgp = msgp; ua.hb = hb; ua.cb = cb;
        ua.init0 = init0; ua.embed0 = embed0; ua.logit = logit; ua.out = out;
        ua.N = N; ua.B = B; ua.iters = 8; ua.BNH = BNH;
        void* args[] = { &ua };
        hipError_t e = hipLaunchCooperativeKernel((const void*)uber_kernel, dim3(NB), dim3(NT),
                                                  args, 0, stream);
        if (e == hipSuccess) return;
        // fall through to multi-kernel path on cooperative-launch failure
        (void)hipGetLastError();   // clear sticky error
    }

    // -------- fallback: round-1 verified multi-kernel path --------
    init_kernel<<<B, H, 0, stream>>>(kk, nn, iw1, ib1, iw2, ib2, iw3, ib3, lng, lnb,
                                     init0, embed0, logit, H);
    {
        long long nb = (BNH + 255) / 256;
        bcast_kernel<<<dim3((unsigned)nb), 256, 0, stream>>>(init0, embed0, hb, cb, embed, BNH, NH);
    }
    {
        CastArgs ca;
        ca.src[0] = mw1; ca.dst[0] = wb_m1; ca.n[0] = H * H;
        ca.src[1] = mw2; ca.dst[1] = wb_m2; ca.n[1] = H * H;
        ca.src[2] = mw3; ca.dst[2] = wb_m3; ca.n[2] = H * H;
        ca.src[3] = wih; ca.dst[3] = wb_ih; ca.n[3] = 4 * H * H;
        ca.src[4] = whh; ca.dst[4] = wb_hh; ca.n[4] = 4 * H * H;
        ca.src[5] = vw1; ca.dst[5] = wb_v1; ca.n[5] = H * H;
        ca.src[6] = vw2; ca.dst[6] = wb_v2; ca.n[6] = H * H;
        castw_kernel<<<dim3(64, 7), 256, 0, stream>>>(ca);
    }
    if (ws_ok) {
        long long n8 = (long long)B * N * N / 8;
        cast8_kernel<<<dim3((unsigned)((n8 + 255) / 256)), 256, 0, stream>>>(x, x8, n8);
    }

    dim3 gridRow(M / 64);
    dim3 gridRow16(M / 16);
    dim3 gridAggNew(N / 128, 4, B);
    dim3 gridAggOld(N / 16, B);

    for (int it = 0; it < 8; ++it) {
        if (ws_ok) {
            msg_mlp_kernel<true><<<gridRow, 256, 0, stream>>>(embed, wb_m1, mb1, wb_m2, mb2,
                                                              wb_m3, mb3, m_t, m8_t, N);
            agg_fp8_kernel<<<gridAggNew, 256, 0, stream>>>(x8, m8_t, msgp, N, BNH);
            gates_lstm_kernel<4, true><<<gridRow16, 256, 0, stream>>>(
                (const void*)msgp, BNH, hb, cb, wb_ih, wb_hh, bih, bhh, lng, lnb, embed);
        } else {
            msg_mlp_kernel<false><<<gridRow, 256, 0, stream>>>(embed, wb_m1, mb1, wb_m2, mb2,
                                                               wb_m3, mb3, m_t, m8_t, N);
            agg_fallback_kernel<<<gridAggOld, 256, 0, stream>>>(x, m_t, (float*)msgp, N);
            gates_lstm_kernel<1, false><<<gridRow16, 256, 0, stream>>>(
                (const void*)msgp, BNH, hb, cb, wb_ih, wb_hh, bih, bhh, lng, lnb, embed);
        }
    }

    vote_mlp_kernel<<<gridRow, 256, 0, stream>>>(embed, wb_v1, vb1, wb_v2, vb2,
                                                 vw3, vb3, mask, logit, N);
    sigmoid_kernel<<<1, 64, 0, stream>>>(logit, out, B);
}

// Round 4
// 1033.928 us; speedup vs baseline: 3.0453x; 3.0453x over previous
//
#include <hip/hip_runtime.h>
#include <cstddef>
#include <cstdint>

#define LN_EPS 1e-5f

typedef __attribute__((ext_vector_type(8))) short bf16x8;
typedef __attribute__((ext_vector_type(4))) float f32x4;

__device__ __forceinline__ unsigned short f2bf(float f) {
    unsigned u = __float_as_uint(f);
    u += 0x7FFFu + ((u >> 16) & 1u);   // round-to-nearest-even
    return (unsigned short)(u >> 16);
}
__device__ __forceinline__ float bf2f(unsigned short s) {
    return __uint_as_float(((unsigned)s) << 16);
}
__device__ __forceinline__ float sigf(float x) { return 1.f / (1.f + __expf(-x)); }

// async global->LDS, 16B per lane. lds dest = wave-uniform base + lane*16.
__device__ __forceinline__ void gload_lds16(const void* g, void* l) {
    __builtin_amdgcn_global_load_lds(
        (const __attribute__((address_space(1))) unsigned int*)(unsigned long long)(uintptr_t)g,
        (__attribute__((address_space(3))) unsigned int*)(unsigned int)(uintptr_t)l,
        16, 0, 0);
}

// ===================== primary path kernels ============================================

// ---- init MLP + LN + msg-MLP(embed0) -> init0, m0 (all fp32, B blocks x 128 thr) ------
__global__ __launch_bounds__(128)
void init_m0_kernel(const float* __restrict__ kk, const float* __restrict__ nn,
                    const float* __restrict__ iw1, const float* __restrict__ ib1,
                    const float* __restrict__ iw2, const float* __restrict__ ib2,
                    const float* __restrict__ iw3, const float* __restrict__ ib3,
                    const float* __restrict__ lng, const float* __restrict__ lnb,
                    const float* __restrict__ mw1, const float* __restrict__ mb1,
                    const float* __restrict__ mw2, const float* __restrict__ mb2,
                    const float* __restrict__ mw3, const float* __restrict__ mb3,
                    float* __restrict__ init0, float* __restrict__ m0,
                    float* __restrict__ logit, int H)
{
    int b = blockIdx.x, j = threadIdx.x;
    __shared__ float s1[128];
    __shared__ float s2[128];
    __shared__ float red[128];
    if (j == 0) logit[b] = 0.f;
    float kv = kk[b], nv = nn[b];
    float h1 = iw1[j * 2 + 0] * kv + iw1[j * 2 + 1] * nv + ib1[j];
    h1 = h1 > 0.f ? h1 : 0.f;
    s1[j] = h1; __syncthreads();
    float h2 = ib2[j];
    for (int q = 0; q < H; ++q) h2 += iw2[j * H + q] * s1[q];
    h2 = h2 > 0.f ? h2 : 0.f;
    s2[j] = h2; __syncthreads();
    float o = ib3[j];
    for (int q = 0; q < H; ++q) o += iw3[j * H + q] * s2[q];
    init0[b * H + j] = o;

    red[j] = o; __syncthreads();
    for (int s = 64; s > 0; s >>= 1) { if (j < s) red[j] += red[j + s]; __syncthreads(); }
    float mu = red[0] / (float)H;
    __syncthreads();
    float d = o - mu;
    red[j] = d * d; __syncthreads();
    for (int s = 64; s > 0; s >>= 1) { if (j < s) red[j] += red[j + s]; __syncthreads(); }
    float var = red[0] / (float)H;
    float e = d * rsqrtf(var + LN_EPS) * lng[j] + lnb[j];

    // msg MLP on embed0 (fp32)
    __syncthreads();
    s1[j] = e; __syncthreads();
    float m1 = mb1[j];
    for (int q = 0; q < H; ++q) m1 += mw1[j * H + q] * s1[q];
    m1 = m1 > 0.f ? m1 : 0.f;
    s2[j] = m1; __syncthreads();
    float m2 = mb2[j];
    for (int q = 0; q < H; ++q) m2 += mw2[j * H + q] * s2[q];
    m2 = m2 > 0.f ? m2 : 0.f;
    __syncthreads();
    s1[j] = m2; __syncthreads();
    float m3 = mb3[j];
    for (int q = 0; q < H; ++q) m3 += mw3[j * H + q] * s1[q];
    m0[b * H + j] = m3;
}

// ---- x -> fp8 + row sums; one block per row -------------------------------------------
__global__ __launch_bounds__(256)
void prep_x_kernel(const float* __restrict__ x, unsigned char* __restrict__ x8,
                   float* __restrict__ rs, int N)
{
    const long long g = blockIdx.x;            // row over B*N
    const float* row = x + g * N;
    unsigned char* orow = x8 + g * N;
    const int t = threadIdx.x;
    const int lane = t & 63, wave = t >> 6;
    float sum = 0.f;
    const int nch = N >> 3;                    // 8-float chunks
    for (int c = t; c < nch; c += 256) {
        float4 a = *(const float4*)(row + c * 8);
        float4 b = *(const float4*)(row + c * 8 + 4);
        sum += a.x + a.y + a.z + a.w + b.x + b.y + b.z + b.w;
        int lo = __builtin_amdgcn_cvt_pk_fp8_f32(a.x, a.y, 0, false);
        lo = __builtin_amdgcn_cvt_pk_fp8_f32(a.z, a.w, lo, true);
        int hi = __builtin_amdgcn_cvt_pk_fp8_f32(b.x, b.y, 0, false);
        hi = __builtin_amdgcn_cvt_pk_fp8_f32(b.z, b.w, hi, true);
        int2 o; o.x = lo; o.y = hi;
        *(int2*)(orow + c * 8) = o;
    }
#pragma unroll
    for (int m = 1; m <= 32; m <<= 1) sum += __shfl_xor(sum, m);
    __shared__ float red[4];
    if (lane == 0) red[wave] = sum;
    __syncthreads();
    if (t == 0) rs[g] = red[0] + red[1] + red[2] + red[3];
}

// ---- weights -> bf16, hb broadcast, cb zero -------------------------------------------
struct PrepArgs {
    const float* wsrc[7];
    unsigned short* wdst[7];
    int wn[7];
    const float* init0;
    unsigned short* hb;
    float* cb;
    long long BNH, NH;
};

__global__ __launch_bounds__(256)
void prep_misc_kernel(PrepArgs P)
{
    const long long gt = (long long)blockIdx.x * 256 + threadIdx.x;
    const long long GT = (long long)gridDim.x * 256;
    for (int rg = 0; rg < 7; ++rg) {
        const float* s = P.wsrc[rg]; unsigned short* d = P.wdst[rg];
        const int n4 = P.wn[rg] >> 2;
        for (long long i = gt; i < n4; i += GT) {
            float4 v = *(const float4*)(s + i * 4);
            ushort4 o;
            o.x = f2bf(v.x); o.y = f2bf(v.y); o.z = f2bf(v.z); o.w = f2bf(v.w);
            *(ushort4*)(d + i * 4) = o;
        }
    }
    const long long n4 = P.BNH >> 2;
    const float4 z4 = make_float4(0.f, 0.f, 0.f, 0.f);
    for (long long i = gt; i < n4; i += GT) {
        const long long idx = i * 4;
        const int b = (int)(idx / P.NH);
        const int j = (int)(idx & 127);
        ushort4 o;
        o.x = f2bf(P.init0[b * 128 + j]);
        o.y = f2bf(P.init0[b * 128 + j + 1]);
        o.z = f2bf(P.init0[b * 128 + j + 2]);
        o.w = f2bf(P.init0[b * 128 + j + 3]);
        ((ushort4*)P.hb)[i] = o;
        ((float4*)P.cb)[i] = z4;
    }
}

// ---- fp8 aggregation: 128x128 C-tile, BK=128, dbuf prefetch, swizzled (verified r1) ---
__global__ __launch_bounds__(256)
void agg_fp8_kernel(const unsigned char* __restrict__ x8,
                    const unsigned char* __restrict__ m8,
                    unsigned short* __restrict__ msgp, int N, long long BNH)
{
    __shared__ unsigned char sA[2][128 * 128];
    __shared__ unsigned char sB[2][128 * 128];

    const int tid = threadIdx.x;
    const int lane = tid & 63, w = tid >> 6;
    const int lr = lane & 15, lq = lane >> 4;
    const int wr = w & 1, wc = w >> 1;
    const int r0 = blockIdx.x * 128;
    const int ksp = blockIdx.y;
    const int batch = blockIdx.z;
    const int kbase = ksp * (N >> 2);
    const int nsteps = (N >> 2) >> 7;

    const unsigned char* xrow = x8 + (long long)batch * N * N;
    const unsigned char* mrow = m8 + (long long)batch * 128 * N;

    f32x4 acc[4][4];
#pragma unroll
    for (int tr = 0; tr < 4; ++tr)
#pragma unroll
        for (int tn = 0; tn < 4; ++tn) acc[tr][tn] = (f32x4)(0.f);

    auto stage = [&](int b, int step) {
        const int k0 = kbase + step * 128;
#pragma unroll
        for (int j = 0; j < 4; ++j) {
            const int c = ((w * 4 + j) << 6) + lane;
            const int row = c >> 3;
            const int gs = (c & 7) ^ (row & 7);
            gload_lds16(xrow + (long long)(r0 + row) * N + k0 + gs * 16,
                        (char*)sA[b] + (w * 4 + j) * 1024);
        }
#pragma unroll
        for (int j = 0; j < 4; ++j) {
            const int c = ((w * 4 + j) << 6) + lane;
            const int row = c >> 3;
            const int gs = (c & 7) ^ (row & 7);
            gload_lds16(mrow + (long long)row * N + k0 + gs * 16,
                        (char*)sB[b] + (w * 4 + j) * 1024);
        }
    };

    stage(0, 0);
    __syncthreads();
    int buf = 0;
    for (int step = 0; step < nsteps; ++step) {
        if (step + 1 < nsteps) stage(buf ^ 1, step + 1);
        const unsigned char* Ab = sA[buf];
        const unsigned char* Bb = sB[buf];
#pragma unroll
        for (int ks = 0; ks < 4; ++ks) {
            const int g    = ks * 4 + lq;
            const int half = (g & 1) << 3;
            const int s16  = g >> 1;
            long af[4], bfr[4];
#pragma unroll
            for (int tr = 0; tr < 4; ++tr) {
                const int row = wr * 64 + tr * 16 + lr;
                af[tr] = *(const long*)(Ab + row * 128 + ((s16 ^ (row & 7)) << 4) + half);
            }
#pragma unroll
            for (int tn = 0; tn < 4; ++tn) {
                const int row = wc * 64 + tn * 16 + lr;
                bfr[tn] = *(const long*)(Bb + row * 128 + ((s16 ^ (row & 7)) << 4) + half);
            }
#pragma unroll
            for (int tr = 0; tr < 4; ++tr)
#pragma unroll
                for (int tn = 0; tn < 4; ++tn)
                    acc[tr][tn] = __builtin_amdgcn_mfma_f32_16x16x32_fp8_fp8(
                        af[tr], bfr[tn], acc[tr][tn], 0, 0, 0);
        }
        __syncthreads();
        buf ^= 1;
    }

    unsigned short* outb = msgp + (long long)ksp * BNH + (long long)(batch * N + r0) * 128;
#pragma unroll
    for (int tr = 0; tr < 4; ++tr)
#pragma unroll
        for (int tn = 0; tn < 4; ++tn)
#pragma unroll
            for (int r = 0; r < 4; ++r)
                outb[(long long)(wr * 64 + tr * 16 + lq * 4 + r) * 128 + wc * 64 + tn * 16 + lr]
                    = f2bf(acc[tr][tn][r]);
}

// ---- fused gates+LSTM+LN then {msg | vote} on one 16-row tile -------------------------
struct FArgs {
    const unsigned short* msgp;
    const float *rs, *m0;
    unsigned short* hb;
    float* cb;
    const unsigned short *wih, *whh;
    const float *bih, *bhh, *lng, *lnb;
    const unsigned short *wm1, *wm2, *wm3;
    const float *mb1, *mb2, *mb3;
    const unsigned short *wv1, *wv2;
    const float *vb1, *vb2, *vw3, *vb3;
    const float* mask;
    float* logit;
    unsigned char* m8;
    int N;
    long long BNH;
};

// MODE: 0 = first iter (gates from rs*m0, then msg); 1 = mid (gates from msgp, then msg);
//       2 = last (gates from msgp, then vote)
template<int MODE>
__global__ __launch_bounds__(256)
void fused_kernel(FArgs A)
{
    __shared__ unsigned short ebt[16][136];
    __shared__ unsigned short act[16][136];
    __shared__ float sred[128];
    __shared__ float sdot[64];
    const int tid = threadIdx.x;
    const int lane = tid & 63, wave = tid >> 6;
    const int lr = lane & 15, lq = lane >> 4;
    const int tile = blockIdx.x;
    const int r0 = tile * 16;
    const int N = A.N;
    const int batch = r0 / N;
    const long long BNH = A.BNH;

    // ================= gates + LSTM + LN (verified body) =================
    f32x4 acc[8];    // tt = gate*2 + half
#pragma unroll
    for (int t = 0; t < 8; ++t) acc[t] = (f32x4)(0.f);

    bf16x8 a[4];
    if constexpr (MODE == 0) {
        const float rsv = A.rs[r0 + lr];
        const float* m0b = A.m0 + batch * 128;
#pragma unroll
        for (int s = 0; s < 4; ++s) {
            bf16x8 r8;
#pragma unroll
            for (int e = 0; e < 8; ++e)
                r8[e] = (short)f2bf(rsv * m0b[s * 32 + lq * 8 + e]);
            a[s] = r8;
        }
    } else {
#pragma unroll
        for (int s = 0; s < 4; ++s) {
            const long long base = (long long)(r0 + lr) * 128 + s * 32 + lq * 8;
            float v[8];
            bf16x8 t0 = *(const bf16x8*)(A.msgp + base);
#pragma unroll
            for (int e = 0; e < 8; ++e) v[e] = bf2f((unsigned short)t0[e]);
#pragma unroll
            for (int j = 1; j < 4; ++j) {
                bf16x8 tj = *(const bf16x8*)(A.msgp + (long long)j * BNH + base);
#pragma unroll
                for (int e = 0; e < 8; ++e) v[e] += bf2f((unsigned short)tj[e]);
            }
            bf16x8 r8;
#pragma unroll
            for (int e = 0; e < 8; ++e) r8[e] = (short)f2bf(v[e]);
            a[s] = r8;
        }
    }
#pragma unroll
    for (int s = 0; s < 4; ++s)
#pragma unroll
        for (int tt = 0; tt < 8; ++tt) {
            const int brow = (tt >> 1) * 128 + wave * 32 + (tt & 1) * 16 + lr;
            bf16x8 b = *(const bf16x8*)(A.wih + brow * 128 + s * 32 + lq * 8);
            acc[tt] = __builtin_amdgcn_mfma_f32_16x16x32_bf16(a[s], b, acc[tt], 0, 0, 0);
        }
#pragma unroll
    for (int s = 0; s < 4; ++s)
        a[s] = *(const bf16x8*)(A.hb + (long long)(r0 + lr) * 128 + s * 32 + lq * 8);
#pragma unroll
    for (int s = 0; s < 4; ++s)
#pragma unroll
        for (int tt = 0; tt < 8; ++tt) {
            const int brow = (tt >> 1) * 128 + wave * 32 + (tt & 1) * 16 + lr;
            bf16x8 b = *(const bf16x8*)(A.whh + brow * 128 + s * 32 + lq * 8);
            acc[tt] = __builtin_amdgcn_mfma_f32_16x16x32_bf16(a[s], b, acc[tt], 0, 0, 0);
        }

    float hn[2][4];
    float4* cw = (float4*)A.cb;
#pragma unroll
    for (int half = 0; half < 2; ++half) {
        const int col = wave * 32 + half * 16 + lr;
        const float bi  = A.bih[col]       + A.bhh[col];
        const float bf_ = A.bih[col + 128] + A.bhh[col + 128];
        const float bg  = A.bih[col + 256] + A.bhh[col + 256];
        const float bo  = A.bih[col + 384] + A.bhh[col + 384];
        const long long cidx = ((long long)tile * 8 + wave * 2 + half) * 64 + lane;
        float4 cold = cw[cidx];
        float co[4] = {cold.x, cold.y, cold.z, cold.w};
        float cn[4];
#pragma unroll
        for (int r = 0; r < 4; ++r) {
            float iv = acc[0 + half][r] + bi;
            float fv = acc[2 + half][r] + bf_;
            float gv = acc[4 + half][r] + bg;
            float ov = acc[6 + half][r] + bo;
            float cc = sigf(fv) * co[r] + sigf(iv) * tanhf(gv);
            cn[r] = cc;
            hn[half][r] = sigf(ov) * tanhf(cc);
        }
        cw[cidx] = make_float4(cn[0], cn[1], cn[2], cn[3]);
    }

    float ps1[4], ps2[4];
#pragma unroll
    for (int r = 0; r < 4; ++r) {
        float s1 = hn[0][r] + hn[1][r];
        float s2 = hn[0][r] * hn[0][r] + hn[1][r] * hn[1][r];
#pragma unroll
        for (int m = 1; m <= 8; m <<= 1) {
            s1 += __shfl_xor(s1, m);
            s2 += __shfl_xor(s2, m);
        }
        ps1[r] = s1; ps2[r] = s2;
    }
    if (lr == 0) {
#pragma unroll
        for (int r = 0; r < 4; ++r) {
            sred[(wave * 16 + lq * 4 + r) * 2 + 0] = ps1[r];
            sred[(wave * 16 + lq * 4 + r) * 2 + 1] = ps2[r];
        }
    }
    __syncthreads();

#pragma unroll
    for (int half = 0; half < 2; ++half) {
        const int col = wave * 32 + half * 16 + lr;
        const float g = A.lng[col], bb = A.lnb[col];
#pragma unroll
        for (int r = 0; r < 4; ++r) {
            const int row = lq * 4 + r;
            float S1 = sred[(row) * 2] + sred[(16 + row) * 2] + sred[(32 + row) * 2] + sred[(48 + row) * 2];
            float S2 = sred[(row) * 2 + 1] + sred[(16 + row) * 2 + 1] + sred[(32 + row) * 2 + 1] + sred[(48 + row) * 2 + 1];
            float mean = S1 * (1.f / 128.f);
            float var  = S2 * (1.f / 128.f) - mean * mean;
            float rsq = rsqrtf(var + LN_EPS);
            A.hb[(long long)(r0 + row) * 128 + col] = f2bf(hn[half][r]);
            ebt[row][col] = f2bf((hn[half][r] - mean) * rsq * g + bb);
        }
    }
    __syncthreads();

    if constexpr (MODE == 2) {
        // ================= vote (verified body) =================
        bf16x8 av[4];
        f32x4 acc2[2];
#pragma unroll
        for (int s = 0; s < 4; ++s) av[s] = *(const bf16x8*)&ebt[lr][s * 32 + lq * 8];
        acc2[0] = (f32x4)(0.f); acc2[1] = (f32x4)(0.f);
#pragma unroll
        for (int s = 0; s < 4; ++s)
#pragma unroll
            for (int t = 0; t < 2; ++t) {
                const int orow = wave * 32 + t * 16 + lr;
                bf16x8 b = *(const bf16x8*)(A.wv1 + orow * 128 + s * 32 + lq * 8);
                acc2[t] = __builtin_amdgcn_mfma_f32_16x16x32_bf16(av[s], b, acc2[t], 0, 0, 0);
            }
#pragma unroll
        for (int t = 0; t < 2; ++t) {
            const int col = wave * 32 + t * 16 + lr;
            const float bb = A.vb1[col];
#pragma unroll
            for (int r = 0; r < 4; ++r) {
                float v = acc2[t][r] + bb; v = v > 0.f ? v : 0.f;
                act[lq * 4 + r][col] = f2bf(v);
            }
        }
        __syncthreads();
#pragma unroll
        for (int s = 0; s < 4; ++s) av[s] = *(const bf16x8*)&act[lr][s * 32 + lq * 8];
        acc2[0] = (f32x4)(0.f); acc2[1] = (f32x4)(0.f);
#pragma unroll
        for (int s = 0; s < 4; ++s)
#pragma unroll
            for (int t = 0; t < 2; ++t) {
                const int orow = wave * 32 + t * 16 + lr;
                bf16x8 b = *(const bf16x8*)(A.wv2 + orow * 128 + s * 32 + lq * 8);
                acc2[t] = __builtin_amdgcn_mfma_f32_16x16x32_bf16(av[s], b, acc2[t], 0, 0, 0);
            }
        float dot[4] = {0.f, 0.f, 0.f, 0.f};
#pragma unroll
        for (int t = 0; t < 2; ++t) {
            const int col = wave * 32 + t * 16 + lr;
            const float bb = A.vb2[col], w3c = A.vw3[col];
#pragma unroll
            for (int r = 0; r < 4; ++r) {
                float v = acc2[t][r] + bb; v = v > 0.f ? v : 0.f;
                dot[r] += v * w3c;
            }
        }
#pragma unroll
        for (int r = 0; r < 4; ++r)
#pragma unroll
            for (int m = 1; m <= 8; m <<= 1) dot[r] += __shfl_xor(dot[r], m);
        if (lr == 0) {
#pragma unroll
            for (int r = 0; r < 4; ++r) sdot[wave * 16 + lq * 4 + r] = dot[r];
        }
        __syncthreads();
        if (wave == 0) {
            const int rin = r0 - batch * N + lr;
            float s = sdot[lr] + sdot[16 + lr] + sdot[32 + lr] + sdot[48 + lr];
            float val = (s + A.vb3[0]) * A.mask[batch * N + rin];
#pragma unroll
            for (int m = 1; m <= 8; m <<= 1) val += __shfl_xor(val, m);
            if (lane == 0) atomicAdd(&A.logit[batch], val);
        }
    } else {
        // ================= msg (verified body) =================
        bf16x8 am[4];
        f32x4 acc2[2];
#pragma unroll
        for (int s = 0; s < 4; ++s) am[s] = *(const bf16x8*)&ebt[lr][s * 32 + lq * 8];
        acc2[0] = (f32x4)(0.f); acc2[1] = (f32x4)(0.f);
#pragma unroll
        for (int s = 0; s < 4; ++s)
#pragma unroll
            for (int t = 0; t < 2; ++t) {
                const int orow = wave * 32 + t * 16 + lr;
                bf16x8 b = *(const bf16x8*)(A.wm1 + orow * 128 + s * 32 + lq * 8);
                acc2[t] = __builtin_amdgcn_mfma_f32_16x16x32_bf16(am[s], b, acc2[t], 0, 0, 0);
            }
#pragma unroll
        for (int t = 0; t < 2; ++t) {
            const int col = wave * 32 + t * 16 + lr;
            const float bb = A.mb1[col];
#pragma unroll
            for (int r = 0; r < 4; ++r) {
                float v = acc2[t][r] + bb; v = v > 0.f ? v : 0.f;
                act[lq * 4 + r][col] = f2bf(v);
            }
        }
        __syncthreads();
#pragma unroll
        for (int s = 0; s < 4; ++s) am[s] = *(const bf16x8*)&act[lr][s * 32 + lq * 8];
        acc2[0] = (f32x4)(0.f); acc2[1] = (f32x4)(0.f);
#pragma unroll
        for (int s = 0; s < 4; ++s)
#pragma unroll
            for (int t = 0; t < 2; ++t) {
                const int orow = wave * 32 + t * 16 + lr;
                bf16x8 b = *(const bf16x8*)(A.wm2 + orow * 128 + s * 32 + lq * 8);
                acc2[t] = __builtin_amdgcn_mfma_f32_16x16x32_bf16(am[s], b, acc2[t], 0, 0, 0);
            }
        __syncthreads();
#pragma unroll
        for (int t = 0; t < 2; ++t) {
            const int col = wave * 32 + t * 16 + lr;
            const float bb = A.mb2[col];
#pragma unroll
            for (int r = 0; r < 4; ++r) {
                float v = acc2[t][r] + bb; v = v > 0.f ? v : 0.f;
                ebt[lq * 4 + r][col] = f2bf(v);
            }
        }
        __syncthreads();
#pragma unroll
        for (int s = 0; s < 4; ++s) am[s] = *(const bf16x8*)&ebt[lr][s * 32 + lq * 8];
        acc2[0] = (f32x4)(0.f); acc2[1] = (f32x4)(0.f);
#pragma unroll
        for (int s = 0; s < 4; ++s)
#pragma unroll
            for (int t = 0; t < 2; ++t) {
                const int orow = wave * 32 + t * 16 + lr;
                bf16x8 b = *(const bf16x8*)(A.wm3 + orow * 128 + s * 32 + lq * 8);
                acc2[t] = __builtin_amdgcn_mfma_f32_16x16x32_bf16(am[s], b, acc2[t], 0, 0, 0);
            }
        const int rin0 = r0 - batch * N + lq * 4;
#pragma unroll
        for (int t = 0; t < 2; ++t) {
            const int col = wave * 32 + t * 16 + lr;
            const float bb = A.mb3[col];
            float v0 = acc2[t][0] + bb, v1 = acc2[t][1] + bb;
            float v2 = acc2[t][2] + bb, v3 = acc2[t][3] + bb;
            int pk = __builtin_amdgcn_cvt_pk_fp8_f32(v0, v1, 0, false);
            pk = __builtin_amdgcn_cvt_pk_fp8_f32(v2, v3, pk, true);
            *(unsigned int*)(A.m8 + (long long)(batch * 128 + col) * N + rin0) = (unsigned)pk;
        }
    }
}

__global__ void sigmoid_kernel(const float* __restrict__ logit, float* __restrict__ out, int B)
{
    int b = threadIdx.x;
    if (b < B) out[b] = 1.f / (1.f + __expf(-logit[b]));
}

// ===================== fallback path (verified round-1 kernels) ========================
__device__ __forceinline__ void layer128(const unsigned short* __restrict__ W,
                                         const bf16x8 a[4], f32x4 acc[8],
                                         int lr, int lq)
{
#pragma unroll
    for (int s = 0; s < 4; ++s) {
#pragma unroll
        for (int tn = 0; tn < 8; ++tn) {
            bf16x8 b = *(const bf16x8*)(W + (tn * 16 + lr) * 128 + s * 32 + lq * 8);
            acc[tn] = __builtin_amdgcn_mfma_f32_16x16x32_bf16(a[s], b, acc[tn], 0, 0, 0);
        }
    }
}

__global__ __launch_bounds__(256)
void msg_mlp_kernel(const unsigned short* __restrict__ embed,
                    const unsigned short* __restrict__ w1, const float* __restrict__ b1,
                    const unsigned short* __restrict__ w2, const float* __restrict__ b2,
                    const unsigned short* __restrict__ w3, const float* __restrict__ b3,
                    unsigned short* __restrict__ m_t, int N)
{
    __shared__ unsigned short sact[4][16][136];
    const int lane = threadIdx.x & 63, wave = threadIdx.x >> 6;
    const int lr = lane & 15, lq = lane >> 4;
    const int r0 = (blockIdx.x * 4 + wave) * 16;

    bf16x8 a[4];
    f32x4 acc[8];

#pragma unroll
    for (int s = 0; s < 4; ++s)
        a[s] = *(const bf16x8*)(embed + (long long)(r0 + lr) * 128 + s * 32 + lq * 8);
#pragma unroll
    for (int tn = 0; tn < 8; ++tn) acc[tn] = (f32x4)(0.f);
    layer128(w1, a, acc, lr, lq);

#pragma unroll
    for (int tn = 0; tn < 8; ++tn) {
        float bb = b1[tn * 16 + lr];
#pragma unroll
        for (int r = 0; r < 4; ++r) {
            float v = acc[tn][r] + bb; v = v > 0.f ? v : 0.f;
            sact[wave][lq * 4 + r][tn * 16 + lr] = f2bf(v);
        }
    }
    __syncthreads();
#pragma unroll
    for (int s = 0; s < 4; ++s)
        a[s] = *(const bf16x8*)&sact[wave][lr][s * 32 + lq * 8];
#pragma unroll
    for (int tn = 0; tn < 8; ++tn) acc[tn] = (f32x4)(0.f);
    layer128(w2, a, acc, lr, lq);

#pragma unroll
    for (int tn = 0; tn < 8; ++tn) {
        float bb = b2[tn * 16 + lr];
#pragma unroll
        for (int r = 0; r < 4; ++r) {
            float v = acc[tn][r] + bb; v = v > 0.f ? v : 0.f;
            sact[wave][lq * 4 + r][tn * 16 + lr] = f2bf(v);
        }
    }
    __syncthreads();
#pragma unroll
    for (int s = 0; s < 4; ++s)
        a[s] = *(const bf16x8*)&sact[wave][lr][s * 32 + lq * 8];
#pragma unroll
    for (int tn = 0; tn < 8; ++tn) acc[tn] = (f32x4)(0.f);
    layer128(w3, a, acc, lr, lq);

    const int batch = r0 / N;
    const int rin0 = r0 - batch * N + lq * 4;
#pragma unroll
    for (int tn = 0; tn < 8; ++tn) {
        float bb = b3[tn * 16 + lr];
        ushort4 o;
        o.x = f2bf(acc[tn][0] + bb); o.y = f2bf(acc[tn][1] + bb);
        o.z = f2bf(acc[tn][2] + bb); o.w = f2bf(acc[tn][3] + bb);
        *(ushort4*)(m_t + ((long long)(batch * 128 + tn * 16 + lr)) * N + rin0) = o;
    }
}

__global__ __launch_bounds__(256)
void agg_fallback_kernel(const float* __restrict__ xf,
                         const unsigned short* __restrict__ mt, float* __restrict__ msgp0,
                         int N)
{
    __shared__ float sacc[4][16][132];
    const int lane = threadIdx.x & 63, wave = threadIdx.x >> 6;
    const int lr = lane & 15, lq = lane >> 4;
    const int batch = blockIdx.y;
    const int rowBase = blockIdx.x * 16;
    const int kBase = wave * (N >> 2);
    const int kIters = N >> 7;

    const float* af = xf + (long long)batch * N * N + (long long)(rowBase + lr) * N + kBase + lq * 8;
    const long long bbase = (long long)batch * 128 * N + (long long)lr * N + kBase + lq * 8;

    f32x4 acc[8];
#pragma unroll
    for (int tn = 0; tn < 8; ++tn) acc[tn] = (f32x4)(0.f);

    for (int it = 0; it < kIters; ++it) {
        const int k = it * 32;
        float4 lo = *(const float4*)(af + k);
        float4 hi = *(const float4*)(af + k + 4);
        bf16x8 a0;
        a0[0] = (short)f2bf(lo.x); a0[1] = (short)f2bf(lo.y);
        a0[2] = (short)f2bf(lo.z); a0[3] = (short)f2bf(lo.w);
        a0[4] = (short)f2bf(hi.x); a0[5] = (short)f2bf(hi.y);
        a0[6] = (short)f2bf(hi.z); a0[7] = (short)f2bf(hi.w);
#pragma unroll
        for (int tn = 0; tn < 8; ++tn) {
            bf16x8 b0 = *(const bf16x8*)(mt + bbase + (long long)tn * 16 * N + k);
            acc[tn] = __builtin_amdgcn_mfma_f32_16x16x32_bf16(a0, b0, acc[tn], 0, 0, 0);
        }
    }

#pragma unroll
    for (int tn = 0; tn < 8; ++tn)
#pragma unroll
        for (int r = 0; r < 4; ++r)
            sacc[wave][lq * 4 + r][tn * 16 + lr] = acc[tn][r];
    __syncthreads();
    {
        const int t = threadIdx.x;
        const int row = t >> 4, cb2 = (t & 15) * 8;
        float o[8];
#pragma unroll
        for (int j = 0; j < 8; ++j)
            o[j] = sacc[0][row][cb2 + j] + sacc[1][row][cb2 + j]
                 + sacc[2][row][cb2 + j] + sacc[3][row][cb2 + j];
        float* dst = msgp0 + (long long)(batch * N + rowBase + row) * 128 + cb2;
        *(float4*)dst = make_float4(o[0], o[1], o[2], o[3]);
        *(float4*)(dst + 4) = make_float4(o[4], o[5], o[6], o[7]);
    }
}

__global__ __launch_bounds__(256)
void gates_lstm_fb_kernel(const float* __restrict__ msgp, long long BNH,
                          unsigned short* hb, float* cb,
                          const unsigned short* __restrict__ wih,
                          const unsigned short* __restrict__ whh,
                          const float* __restrict__ bih, const float* __restrict__ bhh,
                          const float* __restrict__ lng, const float* __restrict__ lnb,
                          unsigned short* __restrict__ embed_out)
{
    __shared__ float sred[4][16][2];
    const int lane = threadIdx.x & 63, wave = threadIdx.x >> 6;
    const int lr = lane & 15, lq = lane >> 4;
    const int r0 = blockIdx.x * 16;

    f32x4 acc[8];
#pragma unroll
    for (int t = 0; t < 8; ++t) acc[t] = (f32x4)(0.f);

    bf16x8 a[4];
#pragma unroll
    for (int s = 0; s < 4; ++s) {
        const long long base = (long long)(r0 + lr) * 128 + s * 32 + lq * 8;
        float4 t0 = *(const float4*)(msgp + base);
        float4 t1 = *(const float4*)(msgp + base + 4);
        bf16x8 r8;
        r8[0] = (short)f2bf(t0.x); r8[1] = (short)f2bf(t0.y);
        r8[2] = (short)f2bf(t0.z); r8[3] = (short)f2bf(t0.w);
        r8[4] = (short)f2bf(t1.x); r8[5] = (short)f2bf(t1.y);
        r8[6] = (short)f2bf(t1.z); r8[7] = (short)f2bf(t1.w);
        a[s] = r8;
    }
#pragma unroll
    for (int s = 0; s < 4; ++s)
#pragma unroll
        for (int tt = 0; tt < 8; ++tt) {
            const int brow = (tt >> 1) * 128 + wave * 32 + (tt & 1) * 16 + lr;
            bf16x8 b = *(const bf16x8*)(wih + brow * 128 + s * 32 + lq * 8);
            acc[tt] = __builtin_amdgcn_mfma_f32_16x16x32_bf16(a[s], b, acc[tt], 0, 0, 0);
        }
#pragma unroll
    for (int s = 0; s < 4; ++s)
        a[s] = *(const bf16x8*)((const unsigned short*)hb + (long long)(r0 + lr) * 128 + s * 32 + lq * 8);
#pragma unroll
    for (int s = 0; s < 4; ++s)
#pragma unroll
        for (int tt = 0; tt < 8; ++tt) {
            const int brow = (tt >> 1) * 128 + wave * 32 + (tt & 1) * 16 + lr;
            bf16x8 b = *(const bf16x8*)(whh + brow * 128 + s * 32 + lq * 8);
            acc[tt] = __builtin_amdgcn_mfma_f32_16x16x32_bf16(a[s], b, acc[tt], 0, 0, 0);
        }

    float hn[2][4];
    float4* cw = (float4*)cb;
#pragma unroll
    for (int half = 0; half < 2; ++half) {
        const int col = wave * 32 + half * 16 + lr;
        const float bi  = bih[col]       + bhh[col];
        const float bf_ = bih[col + 128] + bhh[col + 128];
        const float bg  = bih[col + 256] + bhh[col + 256];
        const float bo  = bih[col + 384] + bhh[col + 384];
        const long long cidx = ((long long)blockIdx.x * 8 + wave * 2 + half) * 64 + lane;
        float4 cold = cw[cidx];
        float co[4] = {cold.x, cold.y, cold.z, cold.w};
        float cn[4];
#pragma unroll
        for (int r = 0; r < 4; ++r) {
            float iv = acc[0 + half][r] + bi;
            float fv = acc[2 + half][r] + bf_;
            float gv = acc[4 + half][r] + bg;
            float ov = acc[6 + half][r] + bo;
            float cc = sigf(fv) * co[r] + sigf(iv) * tanhf(gv);
            cn[r] = cc;
            hn[half][r] = sigf(ov) * tanhf(cc);
        }
        cw[cidx] = make_float4(cn[0], cn[1], cn[2], cn[3]);
    }

    float ps1[4], ps2[4];
#pragma unroll
    for (int r = 0; r < 4; ++r) {
        float s1 = hn[0][r] + hn[1][r];
        float s2 = hn[0][r] * hn[0][r] + hn[1][r] * hn[1][r];
#pragma unroll
        for (int m = 1; m <= 8; m <<= 1) {
            s1 += __shfl_xor(s1, m);
            s2 += __shfl_xor(s2, m);
        }
        ps1[r] = s1; ps2[r] = s2;
    }
    if (lr == 0) {
#pragma unroll
        for (int r = 0; r < 4; ++r) {
            sred[wave][lq * 4 + r][0] = ps1[r];
            sred[wave][lq * 4 + r][1] = ps2[r];
        }
    }
    __syncthreads();

#pragma unroll
    for (int half = 0; half < 2; ++half) {
        const int col = wave * 32 + half * 16 + lr;
        const float g = lng[col], bb = lnb[col];
#pragma unroll
        for (int r = 0; r < 4; ++r) {
            const int row = lq * 4 + r;
            float S1 = sred[0][row][0] + sred[1][row][0] + sred[2][row][0] + sred[3][row][0];
            float S2 = sred[0][row][1] + sred[1][row][1] + sred[2][row][1] + sred[3][row][1];
            float mean = S1 * (1.f / 128.f);
            float var  = S2 * (1.f / 128.f) - mean * mean;
            float rs = rsqrtf(var + LN_EPS);
            long long off = (long long)(r0 + row) * 128 + col;
            hb[off] = f2bf(hn[half][r]);
            embed_out[off] = f2bf((hn[half][r] - mean) * rs * g + bb);
        }
    }
}

__global__ __launch_bounds__(256)
void vote_mlp_kernel(const unsigned short* __restrict__ embed,
                     const unsigned short* __restrict__ w1, const float* __restrict__ b1,
                     const unsigned short* __restrict__ w2, const float* __restrict__ b2,
                     const float* __restrict__ w3, const float* __restrict__ b3p,
                     const float* __restrict__ mask, float* __restrict__ logit, int N)
{
    __shared__ unsigned short sact[4][16][136];
    const int lane = threadIdx.x & 63, wave = threadIdx.x >> 6;
    const int lr = lane & 15, lq = lane >> 4;
    const int r0 = (blockIdx.x * 4 + wave) * 16;

    bf16x8 a[4];
    f32x4 acc[8];
#pragma unroll
    for (int s = 0; s < 4; ++s)
        a[s] = *(const bf16x8*)(embed + (long long)(r0 + lr) * 128 + s * 32 + lq * 8);
#pragma unroll
    for (int tn = 0; tn < 8; ++tn) acc[tn] = (f32x4)(0.f);
    layer128(w1, a, acc, lr, lq);

#pragma unroll
    for (int tn = 0; tn < 8; ++tn) {
        float bb = b1[tn * 16 + lr];
#pragma unroll
        for (int r = 0; r < 4; ++r) {
            float v = acc[tn][r] + bb; v = v > 0.f ? v : 0.f;
            sact[wave][lq * 4 + r][tn * 16 + lr] = f2bf(v);
        }
    }
    __syncthreads();
#pragma unroll
    for (int s = 0; s < 4; ++s)
        a[s] = *(const bf16x8*)&sact[wave][lr][s * 32 + lq * 8];
#pragma unroll
    for (int tn = 0; tn < 8; ++tn) acc[tn] = (f32x4)(0.f);
    layer128(w2, a, acc, lr, lq);

    float dot[4] = {0.f, 0.f, 0.f, 0.f};
#pragma unroll
    for (int tn = 0; tn < 8; ++tn) {
        const int col = tn * 16 + lr;
        const float bb = b2[col], w3c = w3[col];
#pragma unroll
        for (int r = 0; r < 4; ++r) {
            float v = acc[tn][r] + bb; v = v > 0.f ? v : 0.f;
            dot[r] += v * w3c;
        }
    }
#pragma unroll
    for (int r = 0; r < 4; ++r)
#pragma unroll
        for (int m = 1; m <= 8; m <<= 1) dot[r] += __shfl_xor(dot[r], m);

    const int batch = r0 / N;
    const float b3 = b3p[0];
    const int base = r0 + lq * 4;
    float wsum = mask[base + 0] * (dot[0] + b3) + mask[base + 1] * (dot[1] + b3)
               + mask[base + 2] * (dot[2] + b3) + mask[base + 3] * (dot[3] + b3);
    float t = (lr == 0) ? wsum : 0.f;
    t += __shfl_xor(t, 16);
    t += __shfl_xor(t, 32);
    if (lane == 0) atomicAdd(&logit[batch], t);
}

__global__ __launch_bounds__(128)
void init_kernel(const float* __restrict__ kk, const float* __restrict__ nn,
                 const float* __restrict__ w1, const float* __restrict__ b1,
                 const float* __restrict__ w2, const float* __restrict__ b2,
                 const float* __restrict__ w3, const float* __restrict__ b3,
                 const float* __restrict__ lng, const float* __restrict__ lnb,
                 float* __restrict__ init0, float* __restrict__ embed0,
                 float* __restrict__ logit, int H)
{
    int b = blockIdx.x, j = threadIdx.x;
    __shared__ float s1[128];
    __shared__ float s2[128];
    __shared__ float red[128];
    if (j == 0) logit[b] = 0.f;
    float kv = kk[b], nv = nn[b];
    float h1 = w1[j * 2 + 0] * kv + w1[j * 2 + 1] * nv + b1[j];
    h1 = h1 > 0.f ? h1 : 0.f;
    s1[j] = h1; __syncthreads();
    float h2 = b2[j];
    for (int q = 0; q < H; ++q) h2 += w2[j * H + q] * s1[q];
    h2 = h2 > 0.f ? h2 : 0.f;
    s2[j] = h2; __syncthreads();
    float o = b3[j];
    for (int q = 0; q < H; ++q) o += w3[j * H + q] * s2[q];
    init0[b * H + j] = o;

    red[j] = o; __syncthreads();
    for (int s = 64; s > 0; s >>= 1) { if (j < s) red[j] += red[j + s]; __syncthreads(); }
    float mu = red[0] / (float)H;
    __syncthreads();
    float d = o - mu;
    red[j] = d * d; __syncthreads();
    for (int s = 64; s > 0; s >>= 1) { if (j < s) red[j] += red[j + s]; __syncthreads(); }
    float var = red[0] / (float)H;
    embed0[b * H + j] = d * rsqrtf(var + LN_EPS) * lng[j] + lnb[j];
}

__global__ void bcast_kernel(const float* __restrict__ init0, const float* __restrict__ embed0,
                             unsigned short* __restrict__ hb, float* __restrict__ cb,
                             unsigned short* __restrict__ embed,
                             long long total, long long NH)
{
    long long idx = (long long)blockIdx.x * blockDim.x + threadIdx.x;
    if (idx >= total) return;
    int b = (int)(idx / NH);
    int j = (int)(idx & 127);
    hb[idx] = f2bf(init0[b * 128 + j]);
    embed[idx] = f2bf(embed0[b * 128 + j]);
    cb[idx] = 0.f;
}

struct CastArgs {
    const float* src[7];
    unsigned short* dst[7];
    int n[7];
};

__global__ void castw_kernel(CastArgs a)
{
    int rg = blockIdx.y;
    int i = (blockIdx.x * blockDim.x + threadIdx.x) * 4;
    if (i < a.n[rg]) {
        float4 v = *(const float4*)(a.src[rg] + i);
        ushort4 o;
        o.x = f2bf(v.x); o.y = f2bf(v.y); o.z = f2bf(v.z); o.w = f2bf(v.w);
        *(ushort4*)(a.dst[rg] + i) = o;
    }
}

// ---------------- launch ---------------------------------------------------------------
extern "C" void kernel_launch(void* const* d_in, const int* in_sizes, int n_in,
                              void* d_out, int out_size, void* d_ws, size_t ws_size,
                              hipStream_t stream)
{
    const float* x    = (const float*)d_in[0];
    const float* kk   = (const float*)d_in[1];
    const float* nn   = (const float*)d_in[2];
    const float* mask = (const float*)d_in[3];
    const float* iw1  = (const float*)d_in[4];
    const float* ib1  = (const float*)d_in[5];
    const float* iw2  = (const float*)d_in[6];
    const float* ib2  = (const float*)d_in[7];
    const float* iw3  = (const float*)d_in[8];
    const float* ib3  = (const float*)d_in[9];
    const float* mw1  = (const float*)d_in[10];
    const float* mb1  = (const float*)d_in[11];
    const float* mw2  = (const float*)d_in[12];
    const float* mb2  = (const float*)d_in[13];
    const float* mw3  = (const float*)d_in[14];
    const float* mb3  = (const float*)d_in[15];
    const float* wih  = (const float*)d_in[16];
    const float* whh  = (const float*)d_in[17];
    const float* bih  = (const float*)d_in[18];
    const float* bhh  = (const float*)d_in[19];
    const float* lng  = (const float*)d_in[20];
    const float* lnb  = (const float*)d_in[21];
    const float* vw1  = (const float*)d_in[22];
    const float* vb1  = (const float*)d_in[23];
    const float* vw2  = (const float*)d_in[24];
    const float* vb2  = (const float*)d_in[25];
    const float* vw3  = (const float*)d_in[26];
    const float* vb3  = (const float*)d_in[27];
    float* out = (float*)d_out;

    const int B = in_sizes[1];        // 4
    const int H = in_sizes[5];        // 128
    const int N = in_sizes[3] / B;    // 4096
    const long long NH  = (long long)N * H;
    const long long BNH = (long long)B * NH;
    const int M = B * N;

    char* p = (char*)d_ws;
    auto alloc = [&](long long bytes) {
        char* q = p; p += (bytes + 255) & ~255LL; return q;
    };
    float*          cb     = (float*)alloc(BNH * 4);
    unsigned short* embed  = (unsigned short*)alloc(BNH * 2);   // fallback only
    unsigned short* hb     = (unsigned short*)alloc(BNH * 2);
    unsigned short* m_t    = (unsigned short*)alloc(BNH * 2);   // fallback only
    unsigned short* msgp   = (unsigned short*)alloc(4 * BNH * 2);
    float*          init0  = (float*)alloc((long long)B * H * 4);
    float*          embed0 = (float*)alloc((long long)B * H * 4);
    float*          m0     = (float*)alloc((long long)B * H * 4);
    float*          logit  = (float*)alloc((long long)B * 4);
    float*          rs     = (float*)alloc((long long)B * N * 4);
    unsigned short* wb_m1  = (unsigned short*)alloc((long long)H * H * 2);
    unsigned short* wb_m2  = (unsigned short*)alloc((long long)H * H * 2);
    unsigned short* wb_m3  = (unsigned short*)alloc((long long)H * H * 2);
    unsigned short* wb_ih  = (unsigned short*)alloc(4LL * H * H * 2);
    unsigned short* wb_hh  = (unsigned short*)alloc(4LL * H * H * 2);
    unsigned short* wb_v1  = (unsigned short*)alloc((long long)H * H * 2);
    unsigned short* wb_v2  = (unsigned short*)alloc((long long)H * H * 2);
    unsigned char*  m8_t   = (unsigned char*)alloc(BNH);
    unsigned char*  x8     = (unsigned char*)alloc((long long)B * N * N);
    const bool ws_ok = ((long long)(p - (char*)d_ws) <= (long long)ws_size);
    const bool fast = ws_ok && B == 4 && N == 4096 && H == 128;

    if (fast) {
        // prologue (3 dispatches)
        init_m0_kernel<<<B, H, 0, stream>>>(kk, nn, iw1, ib1, iw2, ib2, iw3, ib3,
                                            lng, lnb, mw1, mb1, mw2, mb2, mw3, mb3,
                                            init0, m0, logit, H);
        prep_x_kernel<<<dim3(M), 256, 0, stream>>>(x, x8, rs, N);
        {
            PrepArgs P;
            P.wsrc[0] = mw1; P.wdst[0] = wb_m1; P.wn[0] = H * H;
            P.wsrc[1] = mw2; P.wdst[1] = wb_m2; P.wn[1] = H * H;
            P.wsrc[2] = mw3; P.wdst[2] = wb_m3; P.wn[2] = H * H;
            P.wsrc[3] = wih; P.wdst[3] = wb_ih; P.wn[3] = 4 * H * H;
            P.wsrc[4] = whh; P.wdst[4] = wb_hh; P.wn[4] = 4 * H * H;
            P.wsrc[5] = vw1; P.wdst[5] = wb_v1; P.wn[5] = H * H;
            P.wsrc[6] = vw2; P.wdst[6] = wb_v2; P.wn[6] = H * H;
            P.init0 = init0; P.hb = hb; P.cb = cb; P.BNH = BNH; P.NH = NH;
            prep_misc_kernel<<<dim3(1024), 256, 0, stream>>>(P);
        }

        FArgs F;
        F.msgp = msgp; F.rs = rs; F.m0 = m0;
        F.hb = hb; F.cb = cb;
        F.wih = wb_ih; F.whh = wb_hh; F.bih = bih; F.bhh = bhh; F.lng = lng; F.lnb = lnb;
        F.wm1 = wb_m1; F.wm2 = wb_m2; F.wm3 = wb_m3; F.mb1 = mb1; F.mb2 = mb2; F.mb3 = mb3;
        F.wv1 = wb_v1; F.wv2 = wb_v2; F.vb1 = vb1; F.vb2 = vb2; F.vw3 = vw3; F.vb3 = vb3;
        F.mask = mask; F.logit = logit; F.m8 = m8_t;
        F.N = N; F.BNH = BNH;

        dim3 gridF(M / 16);
        dim3 gridAgg(N / 128, 4, B);

        // iter 0: gates from rs*m0, then msg -> m8
        fused_kernel<0><<<gridF, 256, 0, stream>>>(F);
        // iters 1..7
        for (int it = 1; it < 8; ++it) {
            agg_fp8_kernel<<<gridAgg, 256, 0, stream>>>(x8, m8_t, msgp, N, BNH);
            if (it < 7) fused_kernel<1><<<gridF, 256, 0, stream>>>(F);
            else        fused_kernel<2><<<gridF, 256, 0, stream>>>(F);
        }
        sigmoid_kernel<<<1, 64, 0, stream>>>(logit, out, B);
        return;
    }

    // -------- fallback: verified round-1-style multi-kernel path (fp32 agg) --------
    init_kernel<<<B, H, 0, stream>>>(kk, nn, iw1, ib1, iw2, ib2, iw3, ib3, lng, lnb,
                                     init0, embed0, logit, H);
    {
        long long nb = (BNH + 255) / 256;
        bcast_kernel<<<dim3((unsigned)nb), 256, 0, stream>>>(init0, embed0, hb, cb, embed, BNH, NH);
    }
    {
        CastArgs ca;
        ca.src[0] = mw1; ca.dst[0] = wb_m1; ca.n[0] = H * H;
        ca.src[1] = mw2; ca.dst[1] = wb_m2; ca.n[1] = H * H;
        ca.src[2] = mw3; ca.dst[2] = wb_m3; ca.n[2] = H * H;
        ca.src[3] = wih; ca.dst[3] = wb_ih; ca.n[3] = 4 * H * H;
        ca.src[4] = whh; ca.dst[4] = wb_hh; ca.n[4] = 4 * H * H;
        ca.src[5] = vw1; ca.dst[5] = wb_v1; ca.n[5] = H * H;
        ca.src[6] = vw2; ca.dst[6] = wb_v2; ca.n[6] = H * H;
        castw_kernel<<<dim3(64, 7), 256, 0, stream>>>(ca);
    }

    dim3 gridRow(M / 64);
    dim3 gridRow16(M / 16);
    dim3 gridAggOld(N / 16, B);

    for (int it = 0; it < 8; ++it) {
        msg_mlp_kernel<<<gridRow, 256, 0, stream>>>(embed, wb_m1, mb1, wb_m2, mb2,
                                                    wb_m3, mb3, m_t, N);
        agg_fallback_kernel<<<gridAggOld, 256, 0, stream>>>(x, m_t, (float*)msgp, N);
        gates_lstm_fb_kernel<<<gridRow16, 256, 0, stream>>>((float*)msgp, BNH, hb, cb,
                                                            wb_ih, wb_hh, bih, bhh,
                                                            lng, lnb, embed);
    }

    vote_mlp_kernel<<<gridRow, 256, 0, stream>>>(embed, wb_v1, vb1, wb_v2, vb2,
                                                 vw3, vb3, mask, logit, N);
    sigmoid_kernel<<<1, 64, 0, stream>>>(logit, out, B);
}